// Round 3
// baseline (2199.818 us; speedup 1.0000x reference)
//
#include <hip/hip_runtime.h>

typedef unsigned int u32;
typedef unsigned long long u64;
typedef unsigned short u16;

#define DEVFN static __device__ __forceinline__

constexpr int NPTS = 16384;  // points per batch
constexpr int NC = 512;      // centers per batch
// B=8, K=32, FEAT=256

typedef __attribute__((ext_vector_type(8))) short bf16x8;
typedef __attribute__((ext_vector_type(4))) float f32x4;

#define MFMA16(a, b, c) __builtin_amdgcn_mfma_f32_16x16x32_bf16(a, b, c, 0, 0, 0)

DEVFN u16 bf16rne(float f) {
  u32 b = __float_as_uint(f);
  u32 r = (b + 0x7FFFu + ((b >> 16) & 1u)) >> 16;
  return (u16)r;
}

DEVFN u64 shflx64(u64 v, int m) {
  u32 lo = __shfl_xor((u32)v, m, 64);
  u32 hi = __shfl_xor((u32)(v >> 32), m, 64);
  return ((u64)hi << 32) | lo;
}
DEVFN u64 shfl64(u64 v, int src) {
  u32 lo = __shfl((u32)v, src, 64);
  u32 hi = __shfl((u32)(v >> 32), src, 64);
  return ((u64)hi << 32) | lo;
}

DEVFN void csw(u64& a, u64& b) {
  u64 lo = a < b ? a : b;
  u64 hi = a < b ? b : a;
  a = lo; b = hi;
}

DEVFN u32 spread3(u32 v) {  // 4 bits -> bits 0,3,6,9
  return (v & 1u) | ((v & 2u) << 2) | ((v & 4u) << 4) | ((v & 8u) << 6);
}

// ---------------------------------------------------------------------------
// FPS v2: one block per batch. Morton-binned clusters (256 x 64 pts) with
// bbox pruning; point data pinned in VGPRs (launch_bounds 1024,4 -> 128 cap).
// Selection key = (md_bits, 16383-oidx, sp): exact numpy argmax semantics
// (max min_d, ties -> lowest original index). Pruning skips only provably
// no-op updates (rounding-monotone lower bound, same arithmetic shape).
// ---------------------------------------------------------------------------
__global__ __launch_bounds__(1024, 4) void fps_kernel(const float* __restrict__ xyz,
                                                      float* __restrict__ centers) {
  const int b = blockIdx.x;
  const int t = threadIdx.x;
  const int lane = t & 63;
  const int w = t >> 6;
  const float* xb = xyz + (size_t)b * NPTS * 3;

  __shared__ u32 hist[4096];        // 16KB: counting-sort histogram/offsets
  __shared__ u16 soidx[NPTS];       // 32KB: sorted pos -> original idx
  __shared__ float bboxm[256][6];   // 6KB : per-cluster bbox
  __shared__ u32 ckeyHi[256];       // md-max bits per cluster (for prune test)
  __shared__ u64 amask[4];          // active bitmap (256 bits)
  __shared__ u32 skeyHi[16], skeyLo[16];
  __shared__ u32 gkey[2];
  __shared__ float redB[104];
  __shared__ u32 redW[16];

  // ---- setup: global bbox ----
  float lx = 1e30f, ly = 1e30f, lz = 1e30f;
  float hx = -1e30f, hy = -1e30f, hz = -1e30f;
  u32 mcode[16];
  {
    float ox[16], oy[16], oz[16];
#pragma unroll
    for (int j = 0; j < 16; ++j) {
      int p = t + j * 1024;
      ox[j] = xb[p * 3 + 0];
      oy[j] = xb[p * 3 + 1];
      oz[j] = xb[p * 3 + 2];
      lx = fminf(lx, ox[j]); hx = fmaxf(hx, ox[j]);
      ly = fminf(ly, oy[j]); hy = fmaxf(hy, oy[j]);
      lz = fminf(lz, oz[j]); hz = fmaxf(hz, oz[j]);
    }
#pragma unroll
    for (int s = 32; s; s >>= 1) {
      lx = fminf(lx, __shfl_xor(lx, s, 64)); hx = fmaxf(hx, __shfl_xor(hx, s, 64));
      ly = fminf(ly, __shfl_xor(ly, s, 64)); hy = fmaxf(hy, __shfl_xor(hy, s, 64));
      lz = fminf(lz, __shfl_xor(lz, s, 64)); hz = fmaxf(hz, __shfl_xor(hz, s, 64));
    }
    if (lane == 0) {
      redB[w * 6 + 0] = lx; redB[w * 6 + 1] = hx;
      redB[w * 6 + 2] = ly; redB[w * 6 + 3] = hy;
      redB[w * 6 + 4] = lz; redB[w * 6 + 5] = hz;
    }
    __syncthreads();
    if (t == 0) {
      float a0 = redB[0], a1 = redB[1], a2 = redB[2], a3 = redB[3], a4 = redB[4], a5 = redB[5];
      for (int q = 1; q < 16; ++q) {
        a0 = fminf(a0, redB[q * 6 + 0]); a1 = fmaxf(a1, redB[q * 6 + 1]);
        a2 = fminf(a2, redB[q * 6 + 2]); a3 = fmaxf(a3, redB[q * 6 + 3]);
        a4 = fminf(a4, redB[q * 6 + 4]); a5 = fmaxf(a5, redB[q * 6 + 5]);
      }
      redB[96] = a0; redB[97] = a1; redB[98] = a2;
      redB[99] = a3; redB[100] = a4; redB[101] = a5;
    }
    // init hist while waiting
    hist[t * 4 + 0] = 0; hist[t * 4 + 1] = 0; hist[t * 4 + 2] = 0; hist[t * 4 + 3] = 0;
    __syncthreads();
    lx = redB[96]; hx = redB[97]; ly = redB[98]; hy = redB[99]; lz = redB[100]; hz = redB[101];
    const float sx = 15.999f / fmaxf(hx - lx, 1e-9f);
    const float sy = 15.999f / fmaxf(hy - ly, 1e-9f);
    const float sz = 15.999f / fmaxf(hz - lz, 1e-9f);
#pragma unroll
    for (int j = 0; j < 16; ++j) {
      int ix = min(15, max(0, (int)((ox[j] - lx) * sx)));
      int iy = min(15, max(0, (int)((oy[j] - ly) * sy)));
      int iz = min(15, max(0, (int)((oz[j] - lz) * sz)));
      mcode[j] = spread3((u32)ix) | (spread3((u32)iy) << 1) | (spread3((u32)iz) << 2);
    }
  }
  // ---- histogram ----
#pragma unroll
  for (int j = 0; j < 16; ++j) atomicAdd(&hist[mcode[j]], 1u);
  __syncthreads();
  // ---- exclusive scan over 4096 bins ----
  {
    u32 h0 = hist[t * 4 + 0], h1 = hist[t * 4 + 1], h2 = hist[t * 4 + 2], h3 = hist[t * 4 + 3];
    u32 s = h0 + h1 + h2 + h3;
    u32 incl = s;
#pragma unroll
    for (int d = 1; d < 64; d <<= 1) {
      u32 n = __shfl_up(incl, d, 64);
      if (lane >= d) incl += n;
    }
    if (lane == 63) redW[w] = incl;
    __syncthreads();
    if (t == 0) {
      u32 run = 0;
      for (int q = 0; q < 16; ++q) { u32 tmp = redW[q]; redW[q] = run; run += tmp; }
    }
    __syncthreads();
    u32 exc = incl - s + redW[w];
    hist[t * 4 + 0] = exc;
    hist[t * 4 + 1] = exc + h0;
    hist[t * 4 + 2] = exc + h0 + h1;
    hist[t * 4 + 3] = exc + h0 + h1 + h2;
    __syncthreads();
  }
  // ---- scatter: sorted position -> original index ----
#pragma unroll
  for (int j = 0; j < 16; ++j) {
    u32 p = (u32)(t + j * 1024);
    u32 pos = atomicAdd(&hist[mcode[j]], 1u);
    soidx[pos] = (u16)p;
  }
  __syncthreads();
  // ---- gather sorted points into registers; init md & cluster keys ----
  const u32 spbase = ((u32)(t >> 6) << 10) | (u32)(t & 63);
  float px[16], py[16], pz[16], md[16];
  u32 myHi = 0, myLo = 0;
  const u32 inf10 = __float_as_uint(1e10f);
#pragma unroll
  for (int j = 0; j < 16; ++j) {
    u32 sp = spbase + ((u32)j << 6);
    u32 oidx = (u32)soidx[sp];
    px[j] = xb[oidx * 3 + 0];
    py[j] = xb[oidx * 3 + 1];
    pz[j] = xb[oidx * 3 + 2];
    md[j] = 1e10f;
    u32 low = ((16383u - oidx) << 14) | sp;
#pragma unroll
    for (int s = 32; s; s >>= 1) low = max(low, __shfl_xor(low, s, 64));
    if (lane == j) { myHi = inf10; myLo = low; }
    if (lane == 0) ckeyHi[(w << 4) + j] = inf10;
  }
  // ---- per-cluster bbox ----
#pragma unroll
  for (int j = 0; j < 16; ++j) {
    float a = px[j], bq = px[j], c = py[j], d = py[j], e = pz[j], f = pz[j];
#pragma unroll
    for (int s = 32; s; s >>= 1) {
      a = fminf(a, __shfl_xor(a, s, 64)); bq = fmaxf(bq, __shfl_xor(bq, s, 64));
      c = fminf(c, __shfl_xor(c, s, 64)); d = fmaxf(d, __shfl_xor(d, s, 64));
      e = fminf(e, __shfl_xor(e, s, 64)); f = fmaxf(f, __shfl_xor(f, s, 64));
    }
    if (lane == 0) {
      bboxm[(w << 4) + j][0] = a; bboxm[(w << 4) + j][1] = bq;
      bboxm[(w << 4) + j][2] = c; bboxm[(w << 4) + j][3] = d;
      bboxm[(w << 4) + j][4] = e; bboxm[(w << 4) + j][5] = f;
    }
  }
  __syncthreads();
  float bxl = 0.f, bxh = 0.f, byl = 0.f, byh = 0.f, bzl = 0.f, bzh = 0.f;
  if (t < 256) {
    bxl = bboxm[t][0]; bxh = bboxm[t][1];
    byl = bboxm[t][2]; byh = bboxm[t][3];
    bzl = bboxm[t][4]; bzh = bboxm[t][5];
  }
  float cx = xb[0], cy = xb[1], cz = xb[2];
  if (t == 0) {
    centers[(b * NC) * 3 + 0] = cx;
    centers[(b * NC) * 3 + 1] = cy;
    centers[(b * NC) * 3 + 2] = cz;
  }

  // ---- main loop ----
  for (int i = 1; i < NC; ++i) {
    if (t < 256) {  // prune test, cluster t
      float mdm = __uint_as_float(ckeyHi[t]);
      float ax = fmaxf(0.f, fmaxf(__fsub_rn(bxl, cx), __fsub_rn(cx, bxh)));
      float ay = fmaxf(0.f, fmaxf(__fsub_rn(byl, cy), __fsub_rn(cy, byh)));
      float az = fmaxf(0.f, fmaxf(__fsub_rn(bzl, cz), __fsub_rn(cz, bzh)));
      float dlb = __fadd_rn(__fadd_rn(__fmul_rn(ax, ax), __fmul_rn(ay, ay)), __fmul_rn(az, az));
      u64 bal = __ballot(dlb < mdm);
      if (lane == 0) amask[w] = bal;
    }
    __syncthreads();
    u32 maskw = (u32)(amask[w >> 2] >> ((w & 3) << 4)) & 0xFFFFu;
    maskw = __builtin_amdgcn_readfirstlane(maskw);
#pragma unroll
    for (int j = 0; j < 16; ++j) {
      if (maskw & (1u << j)) {
        float dx = __fsub_rn(px[j], cx);
        float dy = __fsub_rn(py[j], cy);
        float dz = __fsub_rn(pz[j], cz);
        float d = __fadd_rn(__fadd_rn(__fmul_rn(dx, dx), __fmul_rn(dy, dy)), __fmul_rn(dz, dz));
        md[j] = fminf(md[j], d);
        float wmx = md[j];
#pragma unroll
        for (int s = 32; s; s >>= 1) wmx = fmaxf(wmx, __shfl_xor(wmx, s, 64));
        u32 sp = spbase + ((u32)j << 6);
        u32 oidx = (u32)soidx[sp];
        u32 packl = ((16383u - oidx) << 14) | sp;
        u32 low = (md[j] == wmx) ? packl : 0u;
#pragma unroll
        for (int s = 32; s; s >>= 1) low = max(low, __shfl_xor(low, s, 64));
        if (lane == j) { myHi = __float_as_uint(wmx); myLo = low; }
        if (lane == 0) ckeyHi[(w << 4) + j] = __float_as_uint(wmx);
      }
    }
    // wave partial max over its 16 cluster keys (lanes 0..15 hold them)
    u64 kk = (lane < 16) ? (((u64)myHi << 32) | myLo) : 0ull;
#pragma unroll
    for (int s = 8; s; s >>= 1) { u64 o = shflx64(kk, s); kk = o > kk ? o : kk; }
    if (lane == 0) { skeyHi[w] = (u32)(kk >> 32); skeyLo[w] = (u32)kk; }
    __syncthreads();
    if (w == 0) {  // final 16-way reduce by wave 0
      u32 aHi = (lane < 16) ? skeyHi[lane] : 0u;
      u32 aLo = (lane < 16) ? skeyLo[lane] : 0u;
      u64 gk = ((u64)aHi << 32) | aLo;
#pragma unroll
      for (int s = 8; s; s >>= 1) { u64 o = shflx64(gk, s); gk = o > gk ? o : gk; }
      if (lane == 0) { gkey[0] = (u32)(gk >> 32); gkey[1] = (u32)gk; }
    }
    __syncthreads();
    u32 gLo = gkey[1];
    u32 ow = 16383u - (gLo >> 14);
    cx = xb[ow * 3 + 0]; cy = xb[ow * 3 + 1]; cz = xb[ow * 3 + 2];
    if (t == 0) {
      centers[(b * NC + i) * 3 + 0] = cx;
      centers[(b * NC + i) * 3 + 1] = cy;
      centers[(b * NC + i) * 3 + 2] = cz;
    }
  }
}

// ---------------------------------------------------------------------------
// KNN: 8 waves/block, wave = one center. Exact top-32 set by (d, idx).
// ---------------------------------------------------------------------------
__global__ __launch_bounds__(512) void knn_kernel(const float* __restrict__ xyz,
                                                  const float* __restrict__ centers,
                                                  float* __restrict__ grouped) {
  __shared__ float spts[1024 * 3];
  __shared__ u64 cand[8][192];
  __shared__ int ccnt[8];
  const int t = threadIdx.x;
  const int lane = t & 63;
  const int w = t >> 6;
  const int cg = blockIdx.x * 8 + w;   // global center id
  const int b = cg >> 9;               // / 512
  const float* xb = xyz + (size_t)b * NPTS * 3;
  const float cx = centers[cg * 3 + 0];
  const float cy = centers[cg * 3 + 1];
  const float cz = centers[cg * 3 + 2];
  if (lane == 0) ccnt[w] = 0;

  // phase 1: per-lane min (packed (d,idx))
  u64 lmin = ~0ull;
  for (int ch = 0; ch < 16; ++ch) {
    __syncthreads();
    const float* src = xb + ch * 1024 * 3;
#pragma unroll
    for (int q = 0; q < 6; ++q) spts[q * 512 + t] = src[q * 512 + t];
    __syncthreads();
#pragma unroll
    for (int j = 0; j < 16; ++j) {
      int p = lane + j * 64;
      float dx = __fsub_rn(cx, spts[p * 3 + 0]);
      float dy = __fsub_rn(cy, spts[p * 3 + 1]);
      float dz = __fsub_rn(cz, spts[p * 3 + 2]);
      float d = __fadd_rn(__fadd_rn(__fmul_rn(dx, dx), __fmul_rn(dy, dy)), __fmul_rn(dz, dz));
      u64 kk = ((u64)__float_as_uint(d) << 32) | (u64)(u32)(ch * 1024 + p);
      lmin = kk < lmin ? kk : lmin;
    }
  }
  // bitonic sort (ascending) of 64 lane-minima; tau = 32nd smallest
  u64 v = lmin;
  for (int k = 2; k <= 64; k <<= 1)
    for (int j = k >> 1; j > 0; j >>= 1) {
      u64 o = shflx64(v, j);
      bool up = ((lane & k) == 0);
      bool lowr = ((lane & j) == 0);
      u64 mn = v < o ? v : o;
      u64 mx = v < o ? o : v;
      v = (lowr == up) ? mn : mx;
    }
  u64 tau = shfl64(v, 31);
  float tf = __uint_as_float((u32)(tau >> 32));

  // phase 2: collect candidates d <= tf  (guaranteed >= 32 of them)
  for (int ch = 0; ch < 16; ++ch) {
    __syncthreads();
    const float* src = xb + ch * 1024 * 3;
#pragma unroll
    for (int q = 0; q < 6; ++q) spts[q * 512 + t] = src[q * 512 + t];
    __syncthreads();
#pragma unroll
    for (int j = 0; j < 16; ++j) {
      int p = lane + j * 64;
      float dx = __fsub_rn(cx, spts[p * 3 + 0]);
      float dy = __fsub_rn(cy, spts[p * 3 + 1]);
      float dz = __fsub_rn(cz, spts[p * 3 + 2]);
      float d = __fadd_rn(__fadd_rn(__fmul_rn(dx, dx), __fmul_rn(dy, dy)), __fmul_rn(dz, dz));
      if (d <= tf) {
        int pos = atomicAdd(&ccnt[w], 1);
        if (pos < 192) cand[w][pos] = ((u64)__float_as_uint(d) << 32) | (u64)(u32)(ch * 1024 + p);
      }
    }
  }
  __syncthreads();
  int cnt = ccnt[w];
  u32 myn = 0u;  // lane r (<32) keeps r-th nearest neighbor's index
  if (cnt <= 192) {
    u64 c0 = (lane < cnt) ? cand[w][lane] : ~0ull;
    u64 c1 = (64 + lane < cnt) ? cand[w][64 + lane] : ~0ull;
    u64 c2 = (128 + lane < cnt) ? cand[w][128 + lane] : ~0ull;
    csw(c0, c1); csw(c1, c2); csw(c0, c1);  // c0<=c1<=c2
    for (int r = 0; r < 32; ++r) {
      u64 wm = c0;
      for (int s = 32; s; s >>= 1) {
        u64 o = shflx64(wm, s);
        wm = o < wm ? o : wm;
      }
      if (c0 == wm) { c0 = c1; c1 = c2; c2 = ~0ull; }
      if (lane == r) myn = (u32)wm;
    }
  } else {
    // exact slow fallback (astronomically rare): ascending extraction
    u64 last = 0ull;
    for (int r = 0; r < 32; ++r) {
      u64 bb = ~0ull;
      for (int j = 0; j < 256; ++j) {
        int p = lane + j * 64;
        float dx = __fsub_rn(cx, xb[p * 3 + 0]);
        float dy = __fsub_rn(cy, xb[p * 3 + 1]);
        float dz = __fsub_rn(cz, xb[p * 3 + 2]);
        float d = __fadd_rn(__fadd_rn(__fmul_rn(dx, dx), __fmul_rn(dy, dy)), __fmul_rn(dz, dz));
        u64 kk = ((u64)__float_as_uint(d) << 32) | (u64)(u32)p;
        if (r == 0 || kk > last)
          if (kk < bb) bb = kk;
      }
      for (int s = 32; s; s >>= 1) {
        u64 o = shflx64(bb, s);
        bb = o < bb ? o : bb;
      }
      last = bb;
      if (lane == r) myn = (u32)bb;
    }
  }
  if (lane < 32) {
    const float nx = xb[(size_t)myn * 3 + 0];
    const float ny = xb[(size_t)myn * 3 + 1];
    const float nz = xb[(size_t)myn * 3 + 2];
    float* gp = grouped + ((size_t)cg * 32 + lane) * 3;
    gp[0] = __fsub_rn(nx, cx);
    gp[1] = __fsub_rn(ny, cy);
    gp[2] = __fsub_rn(nz, cz);
  }
}

// ---------------------------------------------------------------------------
// Weight prep: fold eval-BN into weights, bf16 + MFMA-fragment-swizzled
// layouts for W2/W3 so the MLP kernel stages LDS with a linear copy.
// ---------------------------------------------------------------------------
__global__ __launch_bounds__(256) void prep_kernel(
    const float* __restrict__ W1, const float* __restrict__ b1,
    const float* __restrict__ g1, const float* __restrict__ be1,
    const float* __restrict__ m1, const float* __restrict__ v1,
    const float* __restrict__ W2, const float* __restrict__ b2,
    const float* __restrict__ g2, const float* __restrict__ be2,
    const float* __restrict__ m2, const float* __restrict__ v2,
    const float* __restrict__ W3,
    float* __restrict__ w1eff, u16* __restrict__ w2L,
    float* __restrict__ t2, u16* __restrict__ w3L) {
  const int tid = blockIdx.x * 256 + threadIdx.x;  // 128 blocks -> 32768
  if (tid < 64) {
    float s = g1[tid] / sqrtf(v1[tid] + 1e-5f);
    w1eff[tid * 4 + 0] = W1[tid * 3 + 0] * s;
    w1eff[tid * 4 + 1] = W1[tid * 3 + 1] * s;
    w1eff[tid * 4 + 2] = W1[tid * 3 + 2] * s;
    w1eff[tid * 4 + 3] = (b1[tid] - m1[tid]) * s + be1[tid];
  }
  if (tid < 128) {
    float s = g2[tid] / sqrtf(v2[tid] + 1e-5f);
    t2[tid] = (b2[tid] - m2[tid]) * s + be2[tid];
  }
  if (tid < 8192) {  // W2eff (128 out x 64 in), bn-scaled, as B-fragments
    int i = tid & 63, o = tid >> 6;
    float s = g2[o] / sqrtf(v2[o] + 1e-5f);
    int kg = i >> 3, j = i & 7;
    w2L[((((kg * 128) + o) * 8) ^ ((kg & 7) * 8)) + j] = bf16rne(W2[o * 64 + i] * s);
  }
  if (tid < 32768) {  // W3 (256 out x 128 in) as B-fragments, split in col-halves
    int i = tid & 127, o = tid >> 7;
    int kg = i >> 3, j = i & 7;
    int h = o >> 7, colh = o & 127;
    w3L[h * 16384 + ((((kg * 128) + colh) * 8) ^ ((kg & 7) * 8)) + j] = bf16rne(W3[o * 128 + i]);
  }
}

// ---------------------------------------------------------------------------
// MLP: 4 centers (128 rows) per 256-thread block; wave = one center.
// L1 on VALU (K=3), L2/L3 as bf16 MFMA GEMMs; fused max-pool + pos epilogue.
// LDS (64KB): [0,16K)=W2 (later W3 half over [0,32K)); [16K,32K)=H1; [32K,64K)=H2.
// ---------------------------------------------------------------------------
__global__ __launch_bounds__(256) void mlp_kernel(
    const float* __restrict__ grouped, const u16* __restrict__ w2L,
    const u16* __restrict__ w3L, const float* __restrict__ w1eff,
    const float* __restrict__ t2, const float* __restrict__ b3,
    const float* __restrict__ Wp, const float* __restrict__ bp,
    const float* __restrict__ centers, float* __restrict__ tokens) {
  __shared__ char lds[65536];
  const int t = threadIdx.x;
  const int lane = t & 63;
  const int w = t >> 6;
  const int l15 = lane & 15;
  const int lg = lane >> 4;
  const int c0 = blockIdx.x * 4;
  {  // stage W2 -> [0,16K)
    const u32* s = (const u32*)w2L;
    u32* d = (u32*)lds;
#pragma unroll
    for (int q = 0; q < 16; ++q) d[q * 256 + t] = s[q * 256 + t];
  }
  {  // H1 = relu(X @ W1eff^T + b1eff), bf16, swizzled -> [16K,32K)
    const int row = t & 127;
    const int oh = (t >> 7) * 32;
    const int cg = c0 + (row >> 5);
    const float* gp = grouped + ((size_t)cg * 32 + (row & 31)) * 3;
    const float gx = gp[0], gy = gp[1], gz = gp[2];
    u16 hv[32];
#pragma unroll
    for (int o = 0; o < 32; ++o) {
      const float4 wvv = ((const float4*)w1eff)[oh + o];
      float h = fmaxf(0.f, gx * wvv.x + gy * wvv.y + gz * wvv.z + wvv.w);
      hv[o] = bf16rne(h);
    }
#pragma unroll
    for (int c4 = 0; c4 < 4; ++c4) {
      uint4 pk;
      pk.x = (u32)hv[c4 * 8 + 0] | ((u32)hv[c4 * 8 + 1] << 16);
      pk.y = (u32)hv[c4 * 8 + 2] | ((u32)hv[c4 * 8 + 3] << 16);
      pk.z = (u32)hv[c4 * 8 + 4] | ((u32)hv[c4 * 8 + 5] << 16);
      pk.w = (u32)hv[c4 * 8 + 6] | ((u32)hv[c4 * 8 + 7] << 16);
      int byte = row * 128 + oh * 2 + c4 * 16;
      *reinterpret_cast<uint4*>(lds + 16384 + (byte ^ ((row & 7) << 4))) = pk;
    }
  }
  __syncthreads();
  // GEMM2: H2(32x128) = H1(32x64) @ W2eff^T, per wave
  f32x4 acc2[2][8];
#pragma unroll
  for (int m = 0; m < 2; ++m)
#pragma unroll
    for (int n = 0; n < 8; ++n) acc2[m][n] = (f32x4){0.f, 0.f, 0.f, 0.f};
#pragma unroll
  for (int ks = 0; ks < 2; ++ks) {
    bf16x8 a[2];
#pragma unroll
    for (int m = 0; m < 2; ++m) {
      int row = w * 32 + m * 16 + l15;
      int byte = row * 128 + (ks * 32 + lg * 8) * 2;
      a[m] = *reinterpret_cast<const bf16x8*>(lds + 16384 + (byte ^ ((row & 7) << 4)));
    }
    const int kg = ks * 4 + lg;
#pragma unroll
    for (int n = 0; n < 8; ++n) {
      int idx = (((kg * 128) + (n * 16 + l15)) * 8) ^ ((kg & 7) * 8);
      bf16x8 bb = *reinterpret_cast<const bf16x8*>((const u16*)lds + idx);
      acc2[0][n] = MFMA16(a[0], bb, acc2[0][n]);
      acc2[1][n] = MFMA16(a[1], bb, acc2[1][n]);
    }
  }
#pragma unroll
  for (int n = 0; n < 8; ++n) {  // relu(acc + t2) -> H2 bf16 swizzled
    const int col = n * 16 + l15;
    const float t2v = t2[col];
#pragma unroll
    for (int m = 0; m < 2; ++m)
#pragma unroll
      for (int r = 0; r < 4; ++r) {
        float vv = fmaxf(0.f, acc2[m][n][r] + t2v);
        int row = w * 32 + m * 16 + lg * 4 + r;
        int byte = row * 256 + col * 2;
        *reinterpret_cast<u16*>(lds + 32768 + (byte ^ ((row & 7) << 4))) = bf16rne(vv);
      }
  }
  __syncthreads();
  const float ccx = centers[(c0 + w) * 3 + 0];
  const float ccy = centers[(c0 + w) * 3 + 1];
  const float ccz = centers[(c0 + w) * 3 + 2];
  float* tok = tokens + (size_t)(c0 + w) * 256;
  for (int h = 0; h < 2; ++h) {
    {  // stage W3 col-half (32KB) -> [0,32K); H2 at [32K,64K) untouched
      const u32* s = (const u32*)w3L + h * 8192;
      u32* d = (u32*)lds;
#pragma unroll
      for (int q = 0; q < 32; ++q) d[q * 256 + t] = s[q * 256 + t];
    }
    __syncthreads();
    f32x4 acc3[2][8];
#pragma unroll
    for (int m = 0; m < 2; ++m)
#pragma unroll
      for (int n = 0; n < 8; ++n) acc3[m][n] = (f32x4){0.f, 0.f, 0.f, 0.f};
#pragma unroll
    for (int ks = 0; ks < 4; ++ks) {
      bf16x8 a[2];
#pragma unroll
      for (int m = 0; m < 2; ++m) {
        int row = w * 32 + m * 16 + l15;
        int byte = row * 256 + (ks * 32 + lg * 8) * 2;
        a[m] = *reinterpret_cast<const bf16x8*>(lds + 32768 + (byte ^ ((row & 7) << 4)));
      }
      const int kg = ks * 4 + lg;
#pragma unroll
      for (int n = 0; n < 8; ++n) {
        int idx = (((kg * 128) + (n * 16 + l15)) * 8) ^ ((kg & 7) * 8);
        bf16x8 bb = *reinterpret_cast<const bf16x8*>((const u16*)lds + idx);
        acc3[0][n] = MFMA16(a[0], bb, acc3[0][n]);
        acc3[1][n] = MFMA16(a[1], bb, acc3[1][n]);
      }
    }
#pragma unroll
    for (int n = 0; n < 8; ++n) {  // max over 32 neighbors + b3 + pos
      float vmx = acc3[0][n][0];
#pragma unroll
      for (int m = 0; m < 2; ++m)
#pragma unroll
        for (int r = 0; r < 4; ++r) vmx = fmaxf(vmx, acc3[m][n][r]);
      vmx = fmaxf(vmx, __shfl_xor(vmx, 16, 64));
      vmx = fmaxf(vmx, __shfl_xor(vmx, 32, 64));
      const int col = h * 128 + n * 16 + l15;
      if (lane < 16) {
        float pos = Wp[col * 3 + 0] * ccx + Wp[col * 3 + 1] * ccy +
                    Wp[col * 3 + 2] * ccz + bp[col] + b3[col];
        tok[col] = vmx + pos;
      }
    }
    __syncthreads();
  }
}

// ---------------------------------------------------------------------------
extern "C" void kernel_launch(void* const* d_in, const int* in_sizes, int n_in,
                              void* d_out, int out_size, void* d_ws, size_t ws_size,
                              hipStream_t stream) {
  const float* xyz = (const float*)d_in[0];
  const float* W1 = (const float*)d_in[1];
  const float* b1 = (const float*)d_in[2];
  const float* g1 = (const float*)d_in[3];
  const float* be1 = (const float*)d_in[4];
  const float* m1 = (const float*)d_in[5];
  const float* v1 = (const float*)d_in[6];
  const float* W2 = (const float*)d_in[7];
  const float* b2 = (const float*)d_in[8];
  const float* g2 = (const float*)d_in[9];
  const float* be2 = (const float*)d_in[10];
  const float* m2 = (const float*)d_in[11];
  const float* v2 = (const float*)d_in[12];
  const float* W3 = (const float*)d_in[13];
  const float* b3 = (const float*)d_in[14];
  const float* Wp = (const float*)d_in[15];
  const float* bp = (const float*)d_in[16];

  char* ws = (char*)d_ws;
  float* grouped = (float*)ws;                      // 4096*32*3 f32 = 1572864 B
  float* w1eff = (float*)(ws + 1572864);            // 64*4 f32     = 1024 B
  u16* w2L = (u16*)(ws + 1573888);                  // 8192 u16     = 16384 B
  float* t2 = (float*)(ws + 1590272);               // 128 f32      = 512 B
  u16* w3L = (u16*)(ws + 1590784);                  // 32768 u16    = 65536 B

  float* centers = (float*)d_out;                   // (8,512,3)
  float* tokens = (float*)d_out + 8 * 512 * 3;      // (8,512,256)

  prep_kernel<<<dim3(128), dim3(256), 0, stream>>>(W1, b1, g1, be1, m1, v1,
                                                   W2, b2, g2, be2, m2, v2, W3,
                                                   w1eff, w2L, t2, w3L);
  fps_kernel<<<dim3(8), dim3(1024), 0, stream>>>(xyz, centers);
  knn_kernel<<<dim3(512), dim3(512), 0, stream>>>(xyz, centers, grouped);
  mlp_kernel<<<dim3(1024), dim3(256), 0, stream>>>(grouped, w2L, w3L, w1eff, t2,
                                                   b3, Wp, bp, centers, tokens);
}

// Round 4
// 1831.455 us; speedup vs baseline: 1.2011x; 1.2011x over previous
//
#include <hip/hip_runtime.h>

typedef unsigned int u32;
typedef unsigned long long u64;
typedef unsigned short u16;

#define DEVFN static __device__ __forceinline__

constexpr int NPTS = 16384;  // points per batch
constexpr int NC = 512;      // centers per batch
// B=8, K=32, FEAT=256

typedef __attribute__((ext_vector_type(8))) short bf16x8;
typedef __attribute__((ext_vector_type(4))) float f32x4;

#define MFMA16(a, b, c) __builtin_amdgcn_mfma_f32_16x16x32_bf16(a, b, c, 0, 0, 0)

DEVFN u16 bf16rne(float f) {
  u32 b = __float_as_uint(f);
  u32 r = (b + 0x7FFFu + ((b >> 16) & 1u)) >> 16;
  return (u16)r;
}

DEVFN u64 shflx64(u64 v, int m) {
  u32 lo = __shfl_xor((u32)v, m, 64);
  u32 hi = __shfl_xor((u32)(v >> 32), m, 64);
  return ((u64)hi << 32) | lo;
}
DEVFN u64 shfl64(u64 v, int src) {
  u32 lo = __shfl((u32)v, src, 64);
  u32 hi = __shfl((u32)(v >> 32), src, 64);
  return ((u64)hi << 32) | lo;
}

DEVFN void csw(u64& a, u64& b) {
  u64 lo = a < b ? a : b;
  u64 hi = a < b ? b : a;
  a = lo; b = hi;
}

DEVFN u32 spread3(u32 v) {  // 4 bits -> bits 0,3,6,9
  return (v & 1u) | ((v & 2u) << 2) | ((v & 4u) << 4) | ((v & 8u) << 6);
}

// ---------------------------------------------------------------------------
// FPS v3: one block per batch. Morton-binned clusters (256 x 64 pts) with
// bbox pruning. Mutable per-point state lives in LDS as a packed u64 key:
//   pkey[sp] = (md_bits<<32) | ((16383-oidx)<<14 | sp)
// md update = u64 min (md>=0 so float order == bit order); cluster key =
// u64 max = (max md, tie -> lowest original index) == numpy argmax.
// Only immutable coords (48 VGPRs) stay in registers -> no spill at cap 64.
// ---------------------------------------------------------------------------
__global__ __launch_bounds__(1024, 4) void fps_kernel(const float* __restrict__ xyz,
                                                      float* __restrict__ centers) {
  const int b = blockIdx.x;
  const int t = threadIdx.x;
  const int lane = t & 63;
  const int w = t >> 6;
  const float* xb = xyz + (size_t)b * NPTS * 3;

  __shared__ u64 pkey[NPTS];       // 128KB: per-point (md, tie) key
  __shared__ u32 hist[2048];       // 8KB  : counting-sort bins (setup only)
  __shared__ float bboxT[6][256];  // 6KB  : per-cluster bbox, transposed
  __shared__ u64 ckey[256];        // 2KB  : per-cluster max key
  __shared__ u64 amask[4];         // active bitmap (256 bits)
  __shared__ u64 skey[16];         // per-wave partial max
  __shared__ u64 gkey;             // global max key
  __shared__ float redB[104];
  __shared__ u32 redW[16];

  const u32 inf10 = __float_as_uint(1e10f);

  // ---- setup: global bbox + morton codes ----
  u32 mcode[16];
  float ox[16], oy[16], oz[16];
  {
    float lx = 1e30f, ly = 1e30f, lz = 1e30f;
    float hx = -1e30f, hy = -1e30f, hz = -1e30f;
#pragma unroll
    for (int j = 0; j < 16; ++j) {
      int p = t + j * 1024;
      ox[j] = xb[p * 3 + 0];
      oy[j] = xb[p * 3 + 1];
      oz[j] = xb[p * 3 + 2];
      lx = fminf(lx, ox[j]); hx = fmaxf(hx, ox[j]);
      ly = fminf(ly, oy[j]); hy = fmaxf(hy, oy[j]);
      lz = fminf(lz, oz[j]); hz = fmaxf(hz, oz[j]);
    }
#pragma unroll
    for (int s = 32; s; s >>= 1) {
      lx = fminf(lx, __shfl_xor(lx, s, 64)); hx = fmaxf(hx, __shfl_xor(hx, s, 64));
      ly = fminf(ly, __shfl_xor(ly, s, 64)); hy = fmaxf(hy, __shfl_xor(hy, s, 64));
      lz = fminf(lz, __shfl_xor(lz, s, 64)); hz = fmaxf(hz, __shfl_xor(hz, s, 64));
    }
    if (lane == 0) {
      redB[w * 6 + 0] = lx; redB[w * 6 + 1] = hx;
      redB[w * 6 + 2] = ly; redB[w * 6 + 3] = hy;
      redB[w * 6 + 4] = lz; redB[w * 6 + 5] = hz;
    }
    hist[t] = 0; hist[t + 1024] = 0;
    __syncthreads();
    if (t == 0) {
      float a0 = redB[0], a1 = redB[1], a2 = redB[2], a3 = redB[3], a4 = redB[4], a5 = redB[5];
      for (int q = 1; q < 16; ++q) {
        a0 = fminf(a0, redB[q * 6 + 0]); a1 = fmaxf(a1, redB[q * 6 + 1]);
        a2 = fminf(a2, redB[q * 6 + 2]); a3 = fmaxf(a3, redB[q * 6 + 3]);
        a4 = fminf(a4, redB[q * 6 + 4]); a5 = fmaxf(a5, redB[q * 6 + 5]);
      }
      redB[96] = a0; redB[97] = a1; redB[98] = a2;
      redB[99] = a3; redB[100] = a4; redB[101] = a5;
    }
    __syncthreads();
    const float glx = redB[96], ghx = redB[97];
    const float gly = redB[98], ghy = redB[99];
    const float glz = redB[100], ghz = redB[101];
    const float sx = 15.999f / fmaxf(ghx - glx, 1e-9f);
    const float sy = 15.999f / fmaxf(ghy - gly, 1e-9f);
    const float sz = 7.999f / fmaxf(ghz - glz, 1e-9f);
#pragma unroll
    for (int j = 0; j < 16; ++j) {
      int ix = min(15, max(0, (int)((ox[j] - glx) * sx)));
      int iy = min(15, max(0, (int)((oy[j] - gly) * sy)));
      int iz = min(7, max(0, (int)((oz[j] - glz) * sz)));
      mcode[j] = spread3((u32)ix) | (spread3((u32)iy) << 1) | (spread3((u32)iz) << 2);
    }
  }
  // ---- histogram (2048 bins) ----
#pragma unroll
  for (int j = 0; j < 16; ++j) atomicAdd(&hist[mcode[j]], 1u);
  __syncthreads();
  // ---- exclusive scan over 2048 bins ----
  {
    u32 h0 = hist[t * 2 + 0], h1 = hist[t * 2 + 1];
    u32 s = h0 + h1;
    u32 incl = s;
#pragma unroll
    for (int d = 1; d < 64; d <<= 1) {
      u32 n = __shfl_up(incl, d, 64);
      if (lane >= d) incl += n;
    }
    if (lane == 63) redW[w] = incl;
    __syncthreads();
    if (t == 0) {
      u32 run = 0;
      for (int q = 0; q < 16; ++q) { u32 tmp = redW[q]; redW[q] = run; run += tmp; }
    }
    __syncthreads();
    u32 exc = incl - s + redW[w];
    hist[t * 2 + 0] = exc;
    hist[t * 2 + 1] = exc + h0;
    __syncthreads();
  }
  // ---- scatter: pkey[pos] temporarily holds original index ----
#pragma unroll
  for (int j = 0; j < 16; ++j) {
    u32 p = (u32)(t + j * 1024);
    u32 pos = atomicAdd(&hist[mcode[j]], 1u);
    pkey[pos] = (u64)p;
  }
  __syncthreads();
  // ---- gather coords into regs; init pkey/ckey/bbox ----
  const u32 spbase = ((u32)w << 10) | (u32)lane;
  float px[16], py[16], pz[16];
#pragma unroll
  for (int j = 0; j < 16; ++j) {
    u32 sp = spbase | ((u32)j << 6);
    u32 oidx = (u32)pkey[sp];          // own slot: read-then-write by same thread
    px[j] = xb[oidx * 3 + 0];
    py[j] = xb[oidx * 3 + 1];
    pz[j] = xb[oidx * 3 + 2];
    pkey[sp] = ((u64)inf10 << 32) | (u64)(((16383u - oidx) << 14) | sp);
    // cluster bbox
    float a = px[j], bq = px[j], c = py[j], d = py[j], e = pz[j], f = pz[j];
#pragma unroll
    for (int s = 32; s; s >>= 1) {
      a = fminf(a, __shfl_xor(a, s, 64)); bq = fmaxf(bq, __shfl_xor(bq, s, 64));
      c = fminf(c, __shfl_xor(c, s, 64)); d = fmaxf(d, __shfl_xor(d, s, 64));
      e = fminf(e, __shfl_xor(e, s, 64)); f = fmaxf(f, __shfl_xor(f, s, 64));
    }
    if (lane == 0) {
      int cl = (w << 4) | j;
      bboxT[0][cl] = a; bboxT[1][cl] = bq;
      bboxT[2][cl] = c; bboxT[3][cl] = d;
      bboxT[4][cl] = e; bboxT[5][cl] = f;
      ckey[cl] = (u64)inf10 << 32;     // hi=inf -> all clusters active in iter 1
    }
  }
  __syncthreads();
  float cx = xb[0], cy = xb[1], cz = xb[2];
  if (t == 0) {
    centers[(b * NC) * 3 + 0] = cx;
    centers[(b * NC) * 3 + 1] = cy;
    centers[(b * NC) * 3 + 2] = cz;
  }

  // ---- main loop ----
  for (int i = 1; i < NC; ++i) {
    if (t < 256) {  // prune test for cluster t
      float mdm = __uint_as_float((u32)(ckey[t] >> 32));
      float ax = fmaxf(0.f, fmaxf(__fsub_rn(bboxT[0][t], cx), __fsub_rn(cx, bboxT[1][t])));
      float ay = fmaxf(0.f, fmaxf(__fsub_rn(bboxT[2][t], cy), __fsub_rn(cy, bboxT[3][t])));
      float az = fmaxf(0.f, fmaxf(__fsub_rn(bboxT[4][t], cz), __fsub_rn(cz, bboxT[5][t])));
      float dlb = __fadd_rn(__fadd_rn(__fmul_rn(ax, ax), __fmul_rn(ay, ay)), __fmul_rn(az, az));
      u64 bal = __ballot(dlb < mdm);
      if (lane == 0) amask[w] = bal;
    }
    __syncthreads();
    u32 maskw = (u32)(amask[w >> 2] >> ((w & 3) << 4)) & 0xFFFFu;
    maskw = __builtin_amdgcn_readfirstlane(maskw);
#pragma unroll
    for (int j = 0; j < 16; ++j) {
      if (maskw & (1u << j)) {
        u32 sp = spbase | ((u32)j << 6);
        float dx = __fsub_rn(px[j], cx);
        float dy = __fsub_rn(py[j], cy);
        float dz = __fsub_rn(pz[j], cz);
        float d = __fadd_rn(__fadd_rn(__fmul_rn(dx, dx), __fmul_rn(dy, dy)), __fmul_rn(dz, dz));
        u64 kold = pkey[sp];
        u64 knew = ((u64)__float_as_uint(d) << 32) | (kold & 0xFFFFFFFFull);
        u64 k = knew < kold ? knew : kold;   // md = min(md, d), tie bits constant
        pkey[sp] = k;
#pragma unroll
        for (int s = 32; s; s >>= 1) { u64 o = shflx64(k, s); k = o > k ? o : k; }
        if (lane == 0) ckey[(w << 4) | j] = k;
      }
    }
    // wave partial max over its 16 cluster keys
    {
      u64 kk = (lane < 16) ? ckey[(w << 4) | lane] : 0ull;
#pragma unroll
      for (int s = 8; s; s >>= 1) { u64 o = shflx64(kk, s); kk = o > kk ? o : kk; }
      if (lane == 0) skey[w] = kk;
    }
    __syncthreads();
    if (w == 0) {
      u64 gk = (lane < 16) ? skey[lane] : 0ull;
#pragma unroll
      for (int s = 8; s; s >>= 1) { u64 o = shflx64(gk, s); gk = o > gk ? o : gk; }
      if (lane == 0) gkey = gk;
    }
    __syncthreads();
    u32 gLo = (u32)gkey;
    u32 ow = 16383u - ((gLo >> 14) & 0x3FFFu);
    cx = xb[ow * 3 + 0]; cy = xb[ow * 3 + 1]; cz = xb[ow * 3 + 2];
    if (t == 0) {
      centers[(b * NC + i) * 3 + 0] = cx;
      centers[(b * NC + i) * 3 + 1] = cy;
      centers[(b * NC + i) * 3 + 2] = cz;
    }
  }
}

// ---------------------------------------------------------------------------
// KNN: 8 waves/block, wave = one center. Exact top-32 set by (d, idx).
// ---------------------------------------------------------------------------
__global__ __launch_bounds__(512) void knn_kernel(const float* __restrict__ xyz,
                                                  const float* __restrict__ centers,
                                                  float* __restrict__ grouped) {
  __shared__ float spts[1024 * 3];
  __shared__ u64 cand[8][192];
  __shared__ int ccnt[8];
  const int t = threadIdx.x;
  const int lane = t & 63;
  const int w = t >> 6;
  const int cg = blockIdx.x * 8 + w;   // global center id
  const int b = cg >> 9;               // / 512
  const float* xb = xyz + (size_t)b * NPTS * 3;
  const float cx = centers[cg * 3 + 0];
  const float cy = centers[cg * 3 + 1];
  const float cz = centers[cg * 3 + 2];
  if (lane == 0) ccnt[w] = 0;

  // phase 1: per-lane min (packed (d,idx))
  u64 lmin = ~0ull;
  for (int ch = 0; ch < 16; ++ch) {
    __syncthreads();
    const float* src = xb + ch * 1024 * 3;
#pragma unroll
    for (int q = 0; q < 6; ++q) spts[q * 512 + t] = src[q * 512 + t];
    __syncthreads();
#pragma unroll
    for (int j = 0; j < 16; ++j) {
      int p = lane + j * 64;
      float dx = __fsub_rn(cx, spts[p * 3 + 0]);
      float dy = __fsub_rn(cy, spts[p * 3 + 1]);
      float dz = __fsub_rn(cz, spts[p * 3 + 2]);
      float d = __fadd_rn(__fadd_rn(__fmul_rn(dx, dx), __fmul_rn(dy, dy)), __fmul_rn(dz, dz));
      u64 kk = ((u64)__float_as_uint(d) << 32) | (u64)(u32)(ch * 1024 + p);
      lmin = kk < lmin ? kk : lmin;
    }
  }
  // bitonic sort (ascending) of 64 lane-minima; tau = 32nd smallest
  u64 v = lmin;
  for (int k = 2; k <= 64; k <<= 1)
    for (int j = k >> 1; j > 0; j >>= 1) {
      u64 o = shflx64(v, j);
      bool up = ((lane & k) == 0);
      bool lowr = ((lane & j) == 0);
      u64 mn = v < o ? v : o;
      u64 mx = v < o ? o : v;
      v = (lowr == up) ? mn : mx;
    }
  u64 tau = shfl64(v, 31);
  float tf = __uint_as_float((u32)(tau >> 32));

  // phase 2: collect candidates d <= tf  (guaranteed >= 32 of them)
  for (int ch = 0; ch < 16; ++ch) {
    __syncthreads();
    const float* src = xb + ch * 1024 * 3;
#pragma unroll
    for (int q = 0; q < 6; ++q) spts[q * 512 + t] = src[q * 512 + t];
    __syncthreads();
#pragma unroll
    for (int j = 0; j < 16; ++j) {
      int p = lane + j * 64;
      float dx = __fsub_rn(cx, spts[p * 3 + 0]);
      float dy = __fsub_rn(cy, spts[p * 3 + 1]);
      float dz = __fsub_rn(cz, spts[p * 3 + 2]);
      float d = __fadd_rn(__fadd_rn(__fmul_rn(dx, dx), __fmul_rn(dy, dy)), __fmul_rn(dz, dz));
      if (d <= tf) {
        int pos = atomicAdd(&ccnt[w], 1);
        if (pos < 192) cand[w][pos] = ((u64)__float_as_uint(d) << 32) | (u64)(u32)(ch * 1024 + p);
      }
    }
  }
  __syncthreads();
  int cnt = ccnt[w];
  u32 myn = 0u;  // lane r (<32) keeps r-th nearest neighbor's index
  if (cnt <= 192) {
    u64 c0 = (lane < cnt) ? cand[w][lane] : ~0ull;
    u64 c1 = (64 + lane < cnt) ? cand[w][64 + lane] : ~0ull;
    u64 c2 = (128 + lane < cnt) ? cand[w][128 + lane] : ~0ull;
    csw(c0, c1); csw(c1, c2); csw(c0, c1);  // c0<=c1<=c2
    for (int r = 0; r < 32; ++r) {
      u64 wm = c0;
      for (int s = 32; s; s >>= 1) {
        u64 o = shflx64(wm, s);
        wm = o < wm ? o : wm;
      }
      if (c0 == wm) { c0 = c1; c1 = c2; c2 = ~0ull; }
      if (lane == r) myn = (u32)wm;
    }
  } else {
    // exact slow fallback (astronomically rare): ascending extraction
    u64 last = 0ull;
    for (int r = 0; r < 32; ++r) {
      u64 bb = ~0ull;
      for (int j = 0; j < 256; ++j) {
        int p = lane + j * 64;
        float dx = __fsub_rn(cx, xb[p * 3 + 0]);
        float dy = __fsub_rn(cy, xb[p * 3 + 1]);
        float dz = __fsub_rn(cz, xb[p * 3 + 2]);
        float d = __fadd_rn(__fadd_rn(__fmul_rn(dx, dx), __fmul_rn(dy, dy)), __fmul_rn(dz, dz));
        u64 kk = ((u64)__float_as_uint(d) << 32) | (u64)(u32)p;
        if (r == 0 || kk > last)
          if (kk < bb) bb = kk;
      }
      for (int s = 32; s; s >>= 1) {
        u64 o = shflx64(bb, s);
        bb = o < bb ? o : bb;
      }
      last = bb;
      if (lane == r) myn = (u32)bb;
    }
  }
  if (lane < 32) {
    const float nx = xb[(size_t)myn * 3 + 0];
    const float ny = xb[(size_t)myn * 3 + 1];
    const float nz = xb[(size_t)myn * 3 + 2];
    float* gp = grouped + ((size_t)cg * 32 + lane) * 3;
    gp[0] = __fsub_rn(nx, cx);
    gp[1] = __fsub_rn(ny, cy);
    gp[2] = __fsub_rn(nz, cz);
  }
}

// ---------------------------------------------------------------------------
// Weight prep: fold eval-BN into weights, bf16 + MFMA-fragment-swizzled
// layouts for W2/W3 so the MLP kernel stages LDS with a linear copy.
// ---------------------------------------------------------------------------
__global__ __launch_bounds__(256) void prep_kernel(
    const float* __restrict__ W1, const float* __restrict__ b1,
    const float* __restrict__ g1, const float* __restrict__ be1,
    const float* __restrict__ m1, const float* __restrict__ v1,
    const float* __restrict__ W2, const float* __restrict__ b2,
    const float* __restrict__ g2, const float* __restrict__ be2,
    const float* __restrict__ m2, const float* __restrict__ v2,
    const float* __restrict__ W3,
    float* __restrict__ w1eff, u16* __restrict__ w2L,
    float* __restrict__ t2, u16* __restrict__ w3L) {
  const int tid = blockIdx.x * 256 + threadIdx.x;  // 128 blocks -> 32768
  if (tid < 64) {
    float s = g1[tid] / sqrtf(v1[tid] + 1e-5f);
    w1eff[tid * 4 + 0] = W1[tid * 3 + 0] * s;
    w1eff[tid * 4 + 1] = W1[tid * 3 + 1] * s;
    w1eff[tid * 4 + 2] = W1[tid * 3 + 2] * s;
    w1eff[tid * 4 + 3] = (b1[tid] - m1[tid]) * s + be1[tid];
  }
  if (tid < 128) {
    float s = g2[tid] / sqrtf(v2[tid] + 1e-5f);
    t2[tid] = (b2[tid] - m2[tid]) * s + be2[tid];
  }
  if (tid < 8192) {  // W2eff (128 out x 64 in), bn-scaled, as B-fragments
    int i = tid & 63, o = tid >> 6;
    float s = g2[o] / sqrtf(v2[o] + 1e-5f);
    int kg = i >> 3, j = i & 7;
    w2L[((((kg * 128) + o) * 8) ^ ((kg & 7) * 8)) + j] = bf16rne(W2[o * 64 + i] * s);
  }
  if (tid < 32768) {  // W3 (256 out x 128 in) as B-fragments, split in col-halves
    int i = tid & 127, o = tid >> 7;
    int kg = i >> 3, j = i & 7;
    int h = o >> 7, colh = o & 127;
    w3L[h * 16384 + ((((kg * 128) + colh) * 8) ^ ((kg & 7) * 8)) + j] = bf16rne(W3[o * 128 + i]);
  }
}

// ---------------------------------------------------------------------------
// MLP: 4 centers (128 rows) per 256-thread block; wave = one center.
// L1 on VALU (K=3), L2/L3 as bf16 MFMA GEMMs; fused max-pool + pos epilogue.
// LDS (64KB): [0,16K)=W2 (later W3 half over [0,32K)); [16K,32K)=H1; [32K,64K)=H2.
// ---------------------------------------------------------------------------
__global__ __launch_bounds__(256) void mlp_kernel(
    const float* __restrict__ grouped, const u16* __restrict__ w2L,
    const u16* __restrict__ w3L, const float* __restrict__ w1eff,
    const float* __restrict__ t2, const float* __restrict__ b3,
    const float* __restrict__ Wp, const float* __restrict__ bp,
    const float* __restrict__ centers, float* __restrict__ tokens) {
  __shared__ char lds[65536];
  const int t = threadIdx.x;
  const int lane = t & 63;
  const int w = t >> 6;
  const int l15 = lane & 15;
  const int lg = lane >> 4;
  const int c0 = blockIdx.x * 4;
  {  // stage W2 -> [0,16K)
    const u32* s = (const u32*)w2L;
    u32* d = (u32*)lds;
#pragma unroll
    for (int q = 0; q < 16; ++q) d[q * 256 + t] = s[q * 256 + t];
  }
  {  // H1 = relu(X @ W1eff^T + b1eff), bf16, swizzled -> [16K,32K)
    const int row = t & 127;
    const int oh = (t >> 7) * 32;
    const int cg = c0 + (row >> 5);
    const float* gp = grouped + ((size_t)cg * 32 + (row & 31)) * 3;
    const float gx = gp[0], gy = gp[1], gz = gp[2];
    u16 hv[32];
#pragma unroll
    for (int o = 0; o < 32; ++o) {
      const float4 wvv = ((const float4*)w1eff)[oh + o];
      float h = fmaxf(0.f, gx * wvv.x + gy * wvv.y + gz * wvv.z + wvv.w);
      hv[o] = bf16rne(h);
    }
#pragma unroll
    for (int c4 = 0; c4 < 4; ++c4) {
      uint4 pk;
      pk.x = (u32)hv[c4 * 8 + 0] | ((u32)hv[c4 * 8 + 1] << 16);
      pk.y = (u32)hv[c4 * 8 + 2] | ((u32)hv[c4 * 8 + 3] << 16);
      pk.z = (u32)hv[c4 * 8 + 4] | ((u32)hv[c4 * 8 + 5] << 16);
      pk.w = (u32)hv[c4 * 8 + 6] | ((u32)hv[c4 * 8 + 7] << 16);
      int byte = row * 128 + oh * 2 + c4 * 16;
      *reinterpret_cast<uint4*>(lds + 16384 + (byte ^ ((row & 7) << 4))) = pk;
    }
  }
  __syncthreads();
  // GEMM2: H2(32x128) = H1(32x64) @ W2eff^T, per wave
  f32x4 acc2[2][8];
#pragma unroll
  for (int m = 0; m < 2; ++m)
#pragma unroll
    for (int n = 0; n < 8; ++n) acc2[m][n] = (f32x4){0.f, 0.f, 0.f, 0.f};
#pragma unroll
  for (int ks = 0; ks < 2; ++ks) {
    bf16x8 a[2];
#pragma unroll
    for (int m = 0; m < 2; ++m) {
      int row = w * 32 + m * 16 + l15;
      int byte = row * 128 + (ks * 32 + lg * 8) * 2;
      a[m] = *reinterpret_cast<const bf16x8*>(lds + 16384 + (byte ^ ((row & 7) << 4)));
    }
    const int kg = ks * 4 + lg;
#pragma unroll
    for (int n = 0; n < 8; ++n) {
      int idx = (((kg * 128) + (n * 16 + l15)) * 8) ^ ((kg & 7) * 8);
      bf16x8 bb = *reinterpret_cast<const bf16x8*>((const u16*)lds + idx);
      acc2[0][n] = MFMA16(a[0], bb, acc2[0][n]);
      acc2[1][n] = MFMA16(a[1], bb, acc2[1][n]);
    }
  }
#pragma unroll
  for (int n = 0; n < 8; ++n) {  // relu(acc + t2) -> H2 bf16 swizzled
    const int col = n * 16 + l15;
    const float t2v = t2[col];
#pragma unroll
    for (int m = 0; m < 2; ++m)
#pragma unroll
      for (int r = 0; r < 4; ++r) {
        float vv = fmaxf(0.f, acc2[m][n][r] + t2v);
        int row = w * 32 + m * 16 + lg * 4 + r;
        int byte = row * 256 + col * 2;
        *reinterpret_cast<u16*>(lds + 32768 + (byte ^ ((row & 7) << 4))) = bf16rne(vv);
      }
  }
  __syncthreads();
  const float ccx = centers[(c0 + w) * 3 + 0];
  const float ccy = centers[(c0 + w) * 3 + 1];
  const float ccz = centers[(c0 + w) * 3 + 2];
  float* tok = tokens + (size_t)(c0 + w) * 256;
  for (int h = 0; h < 2; ++h) {
    {  // stage W3 col-half (32KB) -> [0,32K); H2 at [32K,64K) untouched
      const u32* s = (const u32*)w3L + h * 8192;
      u32* d = (u32*)lds;
#pragma unroll
      for (int q = 0; q < 32; ++q) d[q * 256 + t] = s[q * 256 + t];
    }
    __syncthreads();
    f32x4 acc3[2][8];
#pragma unroll
    for (int m = 0; m < 2; ++m)
#pragma unroll
      for (int n = 0; n < 8; ++n) acc3[m][n] = (f32x4){0.f, 0.f, 0.f, 0.f};
#pragma unroll
    for (int ks = 0; ks < 4; ++ks) {
      bf16x8 a[2];
#pragma unroll
      for (int m = 0; m < 2; ++m) {
        int row = w * 32 + m * 16 + l15;
        int byte = row * 256 + (ks * 32 + lg * 8) * 2;
        a[m] = *reinterpret_cast<const bf16x8*>(lds + 32768 + (byte ^ ((row & 7) << 4)));
      }
      const int kg = ks * 4 + lg;
#pragma unroll
      for (int n = 0; n < 8; ++n) {
        int idx = (((kg * 128) + (n * 16 + l15)) * 8) ^ ((kg & 7) * 8);
        bf16x8 bb = *reinterpret_cast<const bf16x8*>((const u16*)lds + idx);
        acc3[0][n] = MFMA16(a[0], bb, acc3[0][n]);
        acc3[1][n] = MFMA16(a[1], bb, acc3[1][n]);
      }
    }
#pragma unroll
    for (int n = 0; n < 8; ++n) {  // max over 32 neighbors + b3 + pos
      float vmx = acc3[0][n][0];
#pragma unroll
      for (int m = 0; m < 2; ++m)
#pragma unroll
        for (int r = 0; r < 4; ++r) vmx = fmaxf(vmx, acc3[m][n][r]);
      vmx = fmaxf(vmx, __shfl_xor(vmx, 16, 64));
      vmx = fmaxf(vmx, __shfl_xor(vmx, 32, 64));
      const int col = h * 128 + n * 16 + l15;
      if (lane < 16) {
        float pos = Wp[col * 3 + 0] * ccx + Wp[col * 3 + 1] * ccy +
                    Wp[col * 3 + 2] * ccz + bp[col] + b3[col];
        tok[col] = vmx + pos;
      }
    }
    __syncthreads();
  }
}

// ---------------------------------------------------------------------------
extern "C" void kernel_launch(void* const* d_in, const int* in_sizes, int n_in,
                              void* d_out, int out_size, void* d_ws, size_t ws_size,
                              hipStream_t stream) {
  const float* xyz = (const float*)d_in[0];
  const float* W1 = (const float*)d_in[1];
  const float* b1 = (const float*)d_in[2];
  const float* g1 = (const float*)d_in[3];
  const float* be1 = (const float*)d_in[4];
  const float* m1 = (const float*)d_in[5];
  const float* v1 = (const float*)d_in[6];
  const float* W2 = (const float*)d_in[7];
  const float* b2 = (const float*)d_in[8];
  const float* g2 = (const float*)d_in[9];
  const float* be2 = (const float*)d_in[10];
  const float* m2 = (const float*)d_in[11];
  const float* v2 = (const float*)d_in[12];
  const float* W3 = (const float*)d_in[13];
  const float* b3 = (const float*)d_in[14];
  const float* Wp = (const float*)d_in[15];
  const float* bp = (const float*)d_in[16];

  char* ws = (char*)d_ws;
  float* grouped = (float*)ws;                      // 4096*32*3 f32 = 1572864 B
  float* w1eff = (float*)(ws + 1572864);            // 64*4 f32     = 1024 B
  u16* w2L = (u16*)(ws + 1573888);                  // 8192 u16     = 16384 B
  float* t2 = (float*)(ws + 1590272);               // 128 f32      = 512 B
  u16* w3L = (u16*)(ws + 1590784);                  // 32768 u16    = 65536 B

  float* centers = (float*)d_out;                   // (8,512,3)
  float* tokens = (float*)d_out + 8 * 512 * 3;      // (8,512,256)

  prep_kernel<<<dim3(128), dim3(256), 0, stream>>>(W1, b1, g1, be1, m1, v1,
                                                   W2, b2, g2, be2, m2, v2, W3,
                                                   w1eff, w2L, t2, w3L);
  fps_kernel<<<dim3(8), dim3(1024), 0, stream>>>(xyz, centers);
  knn_kernel<<<dim3(512), dim3(512), 0, stream>>>(xyz, centers, grouped);
  mlp_kernel<<<dim3(1024), dim3(256), 0, stream>>>(grouped, w2L, w3L, w1eff, t2,
                                                   b3, Wp, bp, centers, tokens);
}

// Round 5
// 935.349 us; speedup vs baseline: 2.3519x; 1.9580x over previous
//
#include <hip/hip_runtime.h>

typedef unsigned int u32;
typedef unsigned long long u64;
typedef unsigned short u16;

#define DEVFN static __device__ __forceinline__

constexpr int NPTS = 16384;  // points per batch
constexpr int NC = 512;      // centers per batch
// B=8, K=32, FEAT=256

typedef __attribute__((ext_vector_type(8))) short bf16x8;
typedef __attribute__((ext_vector_type(4))) float f32x4;

#define MFMA16(a, b, c) __builtin_amdgcn_mfma_f32_16x16x32_bf16(a, b, c, 0, 0, 0)

DEVFN u16 bf16rne(float f) {
  u32 b = __float_as_uint(f);
  u32 r = (b + 0x7FFFu + ((b >> 16) & 1u)) >> 16;
  return (u16)r;
}

DEVFN u64 shflx64(u64 v, int m) {
  u32 lo = __shfl_xor((u32)v, m, 64);
  u32 hi = __shfl_xor((u32)(v >> 32), m, 64);
  return ((u64)hi << 32) | lo;
}
DEVFN u64 shfl64(u64 v, int src) {
  u32 lo = __shfl((u32)v, src, 64);
  u32 hi = __shfl((u32)(v >> 32), src, 64);
  return ((u64)hi << 32) | lo;
}

DEVFN void csw(u64& a, u64& b) {
  u64 lo = a < b ? a : b;
  u64 hi = a < b ? b : a;
  a = lo; b = hi;
}

DEVFN u32 spread3(u32 v) {  // 4 bits -> bits 0,3,6,9
  return (v & 1u) | ((v & 2u) << 2) | ((v & 4u) << 4) | ((v & 8u) << 6);
}

// ---------------------------------------------------------------------------
// FPS v4: one block per batch. Morton clusters of 64 pts, 4 threads/cluster
// (16 pts each). ALL mutable state in registers: mdkey[16] (md_bits ||
// 16383-oidx), cluster bbox, cluster-max key. Prune test per-thread in regs.
// One __syncthreads per iteration (double-buffered skey; redundant final
// reduce in every wave; winner coords via readfirstlane + scalar L2 load).
// LDS padded to 84KB to force 1 block/CU -> 128-VGPR cap (no spill).
// Exactness: key max == numpy argmax (max md, tie -> lowest index); pruning
// skips only provably no-op updates (monotone rounding lower bound).
// ---------------------------------------------------------------------------
__global__ __launch_bounds__(1024, 4) void fps_kernel(const float* __restrict__ xyz,
                                                      float* __restrict__ centers) {
  const int b = blockIdx.x;
  const int t = threadIdx.x;
  const int lane = t & 63;
  const int w = t >> 6;
  const float* xb = xyz + (size_t)b * NPTS * 3;

  __shared__ char smem[86016];               // padded: force 1 block/CU
  u32* hist = (u32*)smem;                    // [0, 8K)   2048 u32
  u16* soidx = (u16*)(smem + 8192);          // [8K, 40K) 16384 u16
  u64* skeybuf = (u64*)(smem + 40960);       // [40K, +256) 2x16 u64
  float* redB = (float*)(smem + 41216);      // 104 f32
  u32* redW = (u32*)(smem + 41664);          // 16 u32

  const u32 inf10 = __float_as_uint(1e10f);

  // ---- setup: global bbox + morton codes ----
  u32 mcode[16];
  {
    float ox[16], oy[16], oz[16];
    float lx = 1e30f, ly = 1e30f, lz = 1e30f;
    float hx = -1e30f, hy = -1e30f, hz = -1e30f;
#pragma unroll
    for (int j = 0; j < 16; ++j) {
      int p = t + j * 1024;
      ox[j] = xb[p * 3 + 0];
      oy[j] = xb[p * 3 + 1];
      oz[j] = xb[p * 3 + 2];
      lx = fminf(lx, ox[j]); hx = fmaxf(hx, ox[j]);
      ly = fminf(ly, oy[j]); hy = fmaxf(hy, oy[j]);
      lz = fminf(lz, oz[j]); hz = fmaxf(hz, oz[j]);
    }
#pragma unroll
    for (int s = 32; s; s >>= 1) {
      lx = fminf(lx, __shfl_xor(lx, s, 64)); hx = fmaxf(hx, __shfl_xor(hx, s, 64));
      ly = fminf(ly, __shfl_xor(ly, s, 64)); hy = fmaxf(hy, __shfl_xor(hy, s, 64));
      lz = fminf(lz, __shfl_xor(lz, s, 64)); hz = fmaxf(hz, __shfl_xor(hz, s, 64));
    }
    if (lane == 0) {
      redB[w * 6 + 0] = lx; redB[w * 6 + 1] = hx;
      redB[w * 6 + 2] = ly; redB[w * 6 + 3] = hy;
      redB[w * 6 + 4] = lz; redB[w * 6 + 5] = hz;
    }
    hist[t] = 0; hist[t + 1024] = 0;
    __syncthreads();
    if (t == 0) {
      float a0 = redB[0], a1 = redB[1], a2 = redB[2], a3 = redB[3], a4 = redB[4], a5 = redB[5];
      for (int q = 1; q < 16; ++q) {
        a0 = fminf(a0, redB[q * 6 + 0]); a1 = fmaxf(a1, redB[q * 6 + 1]);
        a2 = fminf(a2, redB[q * 6 + 2]); a3 = fmaxf(a3, redB[q * 6 + 3]);
        a4 = fminf(a4, redB[q * 6 + 4]); a5 = fmaxf(a5, redB[q * 6 + 5]);
      }
      redB[96] = a0; redB[97] = a1; redB[98] = a2;
      redB[99] = a3; redB[100] = a4; redB[101] = a5;
    }
    __syncthreads();
    const float glx = redB[96], ghx = redB[97];
    const float gly = redB[98], ghy = redB[99];
    const float glz = redB[100], ghz = redB[101];
    const float sx = 15.999f / fmaxf(ghx - glx, 1e-9f);
    const float sy = 15.999f / fmaxf(ghy - gly, 1e-9f);
    const float sz = 7.999f / fmaxf(ghz - glz, 1e-9f);
#pragma unroll
    for (int j = 0; j < 16; ++j) {
      int ix = min(15, max(0, (int)((ox[j] - glx) * sx)));
      int iy = min(15, max(0, (int)((oy[j] - gly) * sy)));
      int iz = min(7, max(0, (int)((oz[j] - glz) * sz)));
      mcode[j] = spread3((u32)ix) | (spread3((u32)iy) << 1) | (spread3((u32)iz) << 2);
    }
  }
  // ---- histogram (2048 bins) ----
#pragma unroll
  for (int j = 0; j < 16; ++j) atomicAdd(&hist[mcode[j]], 1u);
  __syncthreads();
  // ---- exclusive scan over 2048 bins ----
  {
    u32 h0 = hist[t * 2 + 0], h1 = hist[t * 2 + 1];
    u32 s = h0 + h1;
    u32 incl = s;
#pragma unroll
    for (int d = 1; d < 64; d <<= 1) {
      u32 n = __shfl_up(incl, d, 64);
      if (lane >= d) incl += n;
    }
    if (lane == 63) redW[w] = incl;
    __syncthreads();
    if (t == 0) {
      u32 run = 0;
      for (int q = 0; q < 16; ++q) { u32 tmp = redW[q]; redW[q] = run; run += tmp; }
    }
    __syncthreads();
    u32 exc = incl - s + redW[w];
    hist[t * 2 + 0] = exc;
    hist[t * 2 + 1] = exc + h0;
    __syncthreads();
  }
  // ---- scatter: sorted position -> original index ----
#pragma unroll
  for (int j = 0; j < 16; ++j) {
    u32 p = (u32)(t + j * 1024);
    u32 pos = atomicAdd(&hist[mcode[j]], 1u);
    soidx[pos] = (u16)p;
  }
  __syncthreads();
  // ---- gather: thread owns 16 consecutive sorted points of its cluster ----
  const u32 spbase = (u32)((t >> 2) * 64 + (t & 3) * 16);
  float px[16], py[16], pz[16];
  u64 mdkey[16];
#pragma unroll
  for (int j = 0; j < 16; ++j) {
    u32 oidx = (u32)soidx[spbase + j];
    px[j] = xb[oidx * 3 + 0];
    py[j] = xb[oidx * 3 + 1];
    pz[j] = xb[oidx * 3 + 2];
    mdkey[j] = ((u64)inf10 << 32) | (u64)(16383u - oidx);
  }
  // ---- cluster bbox in registers (2-step shuffle over the 4-lane group) ----
  float bxl = px[0], bxh = px[0], byl = py[0], byh = py[0], bzl = pz[0], bzh = pz[0];
#pragma unroll
  for (int j = 1; j < 16; ++j) {
    bxl = fminf(bxl, px[j]); bxh = fmaxf(bxh, px[j]);
    byl = fminf(byl, py[j]); byh = fmaxf(byh, py[j]);
    bzl = fminf(bzl, pz[j]); bzh = fmaxf(bzh, pz[j]);
  }
#pragma unroll
  for (int s = 1; s <= 2; s <<= 1) {
    bxl = fminf(bxl, __shfl_xor(bxl, s, 64)); bxh = fmaxf(bxh, __shfl_xor(bxh, s, 64));
    byl = fminf(byl, __shfl_xor(byl, s, 64)); byh = fmaxf(byh, __shfl_xor(byh, s, 64));
    bzl = fminf(bzl, __shfl_xor(bzl, s, 64)); bzh = fmaxf(bzh, __shfl_xor(bzh, s, 64));
  }
  float cx = xb[0], cy = xb[1], cz = xb[2];
  if (t == 0) {
    centers[(b * NC) * 3 + 0] = cx;
    centers[(b * NC) * 3 + 1] = cy;
    centers[(b * NC) * 3 + 2] = cz;
  }
  u64 mdmkey = (u64)inf10 << 32;  // cluster-max key (group-uniform)

  // ---- main loop: 1 barrier per iteration ----
  for (int i = 1; i < NC; ++i) {
    float ax = fmaxf(0.f, fmaxf(__fsub_rn(bxl, cx), __fsub_rn(cx, bxh)));
    float ay = fmaxf(0.f, fmaxf(__fsub_rn(byl, cy), __fsub_rn(cy, byh)));
    float az = fmaxf(0.f, fmaxf(__fsub_rn(bzl, cz), __fsub_rn(cz, bzh)));
    float dlb = __fadd_rn(__fadd_rn(__fmul_rn(ax, ax), __fmul_rn(ay, ay)), __fmul_rn(az, az));
    if (dlb < __uint_as_float((u32)(mdmkey >> 32))) {  // group-uniform branch
      u64 lmax = 0ull;
#pragma unroll
      for (int j = 0; j < 16; ++j) {
        float dx = __fsub_rn(px[j], cx);
        float dy = __fsub_rn(py[j], cy);
        float dz = __fsub_rn(pz[j], cz);
        float d = __fadd_rn(__fadd_rn(__fmul_rn(dx, dx), __fmul_rn(dy, dy)), __fmul_rn(dz, dz));
        u64 nk = ((u64)__float_as_uint(d) << 32) | (mdkey[j] & 0xFFFFFFFFull);
        u64 k = nk < mdkey[j] ? nk : mdkey[j];  // md = min(md, d)
        mdkey[j] = k;
        lmax = k > lmax ? k : lmax;
      }
      u64 o1 = shflx64(lmax, 1); lmax = o1 > lmax ? o1 : lmax;
      u64 o2 = shflx64(lmax, 2); lmax = o2 > lmax ? o2 : lmax;
      mdmkey = lmax;
    }
    u64 wk = mdmkey;  // wave max over 16 clusters (groups uniform -> start at 4)
#pragma unroll
    for (int s = 4; s <= 32; s <<= 1) { u64 o = shflx64(wk, s); wk = o > wk ? o : wk; }
    if (lane == 0) skeybuf[(i & 1) * 16 + w] = wk;
    __syncthreads();
    u64 gk = skeybuf[(i & 1) * 16 + (lane & 15)];
#pragma unroll
    for (int s = 1; s <= 8; s <<= 1) { u64 o = shflx64(gk, s); gk = o > gk ? o : gk; }
    u32 ow = 16383u - (u32)gk;  // winner original index
    ow = __builtin_amdgcn_readfirstlane(ow);
    cx = xb[ow * 3 + 0]; cy = xb[ow * 3 + 1]; cz = xb[ow * 3 + 2];
    if (t == 0) {
      centers[(b * NC + i) * 3 + 0] = cx;
      centers[(b * NC + i) * 3 + 1] = cy;
      centers[(b * NC + i) * 3 + 2] = cz;
    }
  }
}

// ---------------------------------------------------------------------------
// KNN: 8 waves/block, wave = one center. Exact top-32 set by (d, idx).
// ---------------------------------------------------------------------------
__global__ __launch_bounds__(512) void knn_kernel(const float* __restrict__ xyz,
                                                  const float* __restrict__ centers,
                                                  float* __restrict__ grouped) {
  __shared__ float spts[1024 * 3];
  __shared__ u64 cand[8][192];
  __shared__ int ccnt[8];
  const int t = threadIdx.x;
  const int lane = t & 63;
  const int w = t >> 6;
  const int cg = blockIdx.x * 8 + w;   // global center id
  const int b = cg >> 9;               // / 512
  const float* xb = xyz + (size_t)b * NPTS * 3;
  const float cx = centers[cg * 3 + 0];
  const float cy = centers[cg * 3 + 1];
  const float cz = centers[cg * 3 + 2];
  if (lane == 0) ccnt[w] = 0;

  // phase 1: per-lane min (packed (d,idx))
  u64 lmin = ~0ull;
  for (int ch = 0; ch < 16; ++ch) {
    __syncthreads();
    const float* src = xb + ch * 1024 * 3;
#pragma unroll
    for (int q = 0; q < 6; ++q) spts[q * 512 + t] = src[q * 512 + t];
    __syncthreads();
#pragma unroll
    for (int j = 0; j < 16; ++j) {
      int p = lane + j * 64;
      float dx = __fsub_rn(cx, spts[p * 3 + 0]);
      float dy = __fsub_rn(cy, spts[p * 3 + 1]);
      float dz = __fsub_rn(cz, spts[p * 3 + 2]);
      float d = __fadd_rn(__fadd_rn(__fmul_rn(dx, dx), __fmul_rn(dy, dy)), __fmul_rn(dz, dz));
      u64 kk = ((u64)__float_as_uint(d) << 32) | (u64)(u32)(ch * 1024 + p);
      lmin = kk < lmin ? kk : lmin;
    }
  }
  // bitonic sort (ascending) of 64 lane-minima; tau = 32nd smallest
  u64 v = lmin;
  for (int k = 2; k <= 64; k <<= 1)
    for (int j = k >> 1; j > 0; j >>= 1) {
      u64 o = shflx64(v, j);
      bool up = ((lane & k) == 0);
      bool lowr = ((lane & j) == 0);
      u64 mn = v < o ? v : o;
      u64 mx = v < o ? o : v;
      v = (lowr == up) ? mn : mx;
    }
  u64 tau = shfl64(v, 31);
  float tf = __uint_as_float((u32)(tau >> 32));

  // phase 2: collect candidates d <= tf  (guaranteed >= 32 of them)
  for (int ch = 0; ch < 16; ++ch) {
    __syncthreads();
    const float* src = xb + ch * 1024 * 3;
#pragma unroll
    for (int q = 0; q < 6; ++q) spts[q * 512 + t] = src[q * 512 + t];
    __syncthreads();
#pragma unroll
    for (int j = 0; j < 16; ++j) {
      int p = lane + j * 64;
      float dx = __fsub_rn(cx, spts[p * 3 + 0]);
      float dy = __fsub_rn(cy, spts[p * 3 + 1]);
      float dz = __fsub_rn(cz, spts[p * 3 + 2]);
      float d = __fadd_rn(__fadd_rn(__fmul_rn(dx, dx), __fmul_rn(dy, dy)), __fmul_rn(dz, dz));
      if (d <= tf) {
        int pos = atomicAdd(&ccnt[w], 1);
        if (pos < 192) cand[w][pos] = ((u64)__float_as_uint(d) << 32) | (u64)(u32)(ch * 1024 + p);
      }
    }
  }
  __syncthreads();
  int cnt = ccnt[w];
  u32 myn = 0u;  // lane r (<32) keeps r-th nearest neighbor's index
  if (cnt <= 192) {
    u64 c0 = (lane < cnt) ? cand[w][lane] : ~0ull;
    u64 c1 = (64 + lane < cnt) ? cand[w][64 + lane] : ~0ull;
    u64 c2 = (128 + lane < cnt) ? cand[w][128 + lane] : ~0ull;
    csw(c0, c1); csw(c1, c2); csw(c0, c1);  // c0<=c1<=c2
    for (int r = 0; r < 32; ++r) {
      u64 wm = c0;
      for (int s = 32; s; s >>= 1) {
        u64 o = shflx64(wm, s);
        wm = o < wm ? o : wm;
      }
      if (c0 == wm) { c0 = c1; c1 = c2; c2 = ~0ull; }
      if (lane == r) myn = (u32)wm;
    }
  } else {
    // exact slow fallback (astronomically rare): ascending extraction
    u64 last = 0ull;
    for (int r = 0; r < 32; ++r) {
      u64 bb = ~0ull;
      for (int j = 0; j < 256; ++j) {
        int p = lane + j * 64;
        float dx = __fsub_rn(cx, xb[p * 3 + 0]);
        float dy = __fsub_rn(cy, xb[p * 3 + 1]);
        float dz = __fsub_rn(cz, xb[p * 3 + 2]);
        float d = __fadd_rn(__fadd_rn(__fmul_rn(dx, dx), __fmul_rn(dy, dy)), __fmul_rn(dz, dz));
        u64 kk = ((u64)__float_as_uint(d) << 32) | (u64)(u32)p;
        if (r == 0 || kk > last)
          if (kk < bb) bb = kk;
      }
      for (int s = 32; s; s >>= 1) {
        u64 o = shflx64(bb, s);
        bb = o < bb ? o : bb;
      }
      last = bb;
      if (lane == r) myn = (u32)bb;
    }
  }
  if (lane < 32) {
    const float nx = xb[(size_t)myn * 3 + 0];
    const float ny = xb[(size_t)myn * 3 + 1];
    const float nz = xb[(size_t)myn * 3 + 2];
    float* gp = grouped + ((size_t)cg * 32 + lane) * 3;
    gp[0] = __fsub_rn(nx, cx);
    gp[1] = __fsub_rn(ny, cy);
    gp[2] = __fsub_rn(nz, cz);
  }
}

// ---------------------------------------------------------------------------
// Weight prep: fold eval-BN into weights, bf16 + MFMA-fragment-swizzled
// layouts for W2/W3 so the MLP kernel stages LDS with a linear copy.
// ---------------------------------------------------------------------------
__global__ __launch_bounds__(256) void prep_kernel(
    const float* __restrict__ W1, const float* __restrict__ b1,
    const float* __restrict__ g1, const float* __restrict__ be1,
    const float* __restrict__ m1, const float* __restrict__ v1,
    const float* __restrict__ W2, const float* __restrict__ b2,
    const float* __restrict__ g2, const float* __restrict__ be2,
    const float* __restrict__ m2, const float* __restrict__ v2,
    const float* __restrict__ W3,
    float* __restrict__ w1eff, u16* __restrict__ w2L,
    float* __restrict__ t2, u16* __restrict__ w3L) {
  const int tid = blockIdx.x * 256 + threadIdx.x;  // 128 blocks -> 32768
  if (tid < 64) {
    float s = g1[tid] / sqrtf(v1[tid] + 1e-5f);
    w1eff[tid * 4 + 0] = W1[tid * 3 + 0] * s;
    w1eff[tid * 4 + 1] = W1[tid * 3 + 1] * s;
    w1eff[tid * 4 + 2] = W1[tid * 3 + 2] * s;
    w1eff[tid * 4 + 3] = (b1[tid] - m1[tid]) * s + be1[tid];
  }
  if (tid < 128) {
    float s = g2[tid] / sqrtf(v2[tid] + 1e-5f);
    t2[tid] = (b2[tid] - m2[tid]) * s + be2[tid];
  }
  if (tid < 8192) {  // W2eff (128 out x 64 in), bn-scaled, as B-fragments
    int i = tid & 63, o = tid >> 6;
    float s = g2[o] / sqrtf(v2[o] + 1e-5f);
    int kg = i >> 3, j = i & 7;
    w2L[((((kg * 128) + o) * 8) ^ ((kg & 7) * 8)) + j] = bf16rne(W2[o * 64 + i] * s);
  }
  if (tid < 32768) {  // W3 (256 out x 128 in) as B-fragments, split in col-halves
    int i = tid & 127, o = tid >> 7;
    int kg = i >> 3, j = i & 7;
    int h = o >> 7, colh = o & 127;
    w3L[h * 16384 + ((((kg * 128) + colh) * 8) ^ ((kg & 7) * 8)) + j] = bf16rne(W3[o * 128 + i]);
  }
}

// ---------------------------------------------------------------------------
// MLP: 4 centers (128 rows) per 256-thread block; wave = one center.
// L1 on VALU (K=3), L2/L3 as bf16 MFMA GEMMs; fused max-pool + pos epilogue.
// LDS (64KB): [0,16K)=W2 (later W3 half over [0,32K)); [16K,32K)=H1; [32K,64K)=H2.
// ---------------------------------------------------------------------------
__global__ __launch_bounds__(256) void mlp_kernel(
    const float* __restrict__ grouped, const u16* __restrict__ w2L,
    const u16* __restrict__ w3L, const float* __restrict__ w1eff,
    const float* __restrict__ t2, const float* __restrict__ b3,
    const float* __restrict__ Wp, const float* __restrict__ bp,
    const float* __restrict__ centers, float* __restrict__ tokens) {
  __shared__ char lds[65536];
  const int t = threadIdx.x;
  const int lane = t & 63;
  const int w = t >> 6;
  const int l15 = lane & 15;
  const int lg = lane >> 4;
  const int c0 = blockIdx.x * 4;
  {  // stage W2 -> [0,16K)
    const u32* s = (const u32*)w2L;
    u32* d = (u32*)lds;
#pragma unroll
    for (int q = 0; q < 16; ++q) d[q * 256 + t] = s[q * 256 + t];
  }
  {  // H1 = relu(X @ W1eff^T + b1eff), bf16, swizzled -> [16K,32K)
    const int row = t & 127;
    const int oh = (t >> 7) * 32;
    const int cg = c0 + (row >> 5);
    const float* gp = grouped + ((size_t)cg * 32 + (row & 31)) * 3;
    const float gx = gp[0], gy = gp[1], gz = gp[2];
    u16 hv[32];
#pragma unroll
    for (int o = 0; o < 32; ++o) {
      const float4 wvv = ((const float4*)w1eff)[oh + o];
      float h = fmaxf(0.f, gx * wvv.x + gy * wvv.y + gz * wvv.z + wvv.w);
      hv[o] = bf16rne(h);
    }
#pragma unroll
    for (int c4 = 0; c4 < 4; ++c4) {
      uint4 pk;
      pk.x = (u32)hv[c4 * 8 + 0] | ((u32)hv[c4 * 8 + 1] << 16);
      pk.y = (u32)hv[c4 * 8 + 2] | ((u32)hv[c4 * 8 + 3] << 16);
      pk.z = (u32)hv[c4 * 8 + 4] | ((u32)hv[c4 * 8 + 5] << 16);
      pk.w = (u32)hv[c4 * 8 + 6] | ((u32)hv[c4 * 8 + 7] << 16);
      int byte = row * 128 + oh * 2 + c4 * 16;
      *reinterpret_cast<uint4*>(lds + 16384 + (byte ^ ((row & 7) << 4))) = pk;
    }
  }
  __syncthreads();
  // GEMM2: H2(32x128) = H1(32x64) @ W2eff^T, per wave
  f32x4 acc2[2][8];
#pragma unroll
  for (int m = 0; m < 2; ++m)
#pragma unroll
    for (int n = 0; n < 8; ++n) acc2[m][n] = (f32x4){0.f, 0.f, 0.f, 0.f};
#pragma unroll
  for (int ks = 0; ks < 2; ++ks) {
    bf16x8 a[2];
#pragma unroll
    for (int m = 0; m < 2; ++m) {
      int row = w * 32 + m * 16 + l15;
      int byte = row * 128 + (ks * 32 + lg * 8) * 2;
      a[m] = *reinterpret_cast<const bf16x8*>(lds + 16384 + (byte ^ ((row & 7) << 4)));
    }
    const int kg = ks * 4 + lg;
#pragma unroll
    for (int n = 0; n < 8; ++n) {
      int idx = (((kg * 128) + (n * 16 + l15)) * 8) ^ ((kg & 7) * 8);
      bf16x8 bb = *reinterpret_cast<const bf16x8*>((const u16*)lds + idx);
      acc2[0][n] = MFMA16(a[0], bb, acc2[0][n]);
      acc2[1][n] = MFMA16(a[1], bb, acc2[1][n]);
    }
  }
#pragma unroll
  for (int n = 0; n < 8; ++n) {  // relu(acc + t2) -> H2 bf16 swizzled
    const int col = n * 16 + l15;
    const float t2v = t2[col];
#pragma unroll
    for (int m = 0; m < 2; ++m)
#pragma unroll
      for (int r = 0; r < 4; ++r) {
        float vv = fmaxf(0.f, acc2[m][n][r] + t2v);
        int row = w * 32 + m * 16 + lg * 4 + r;
        int byte = row * 256 + col * 2;
        *reinterpret_cast<u16*>(lds + 32768 + (byte ^ ((row & 7) << 4))) = bf16rne(vv);
      }
  }
  __syncthreads();
  const float ccx = centers[(c0 + w) * 3 + 0];
  const float ccy = centers[(c0 + w) * 3 + 1];
  const float ccz = centers[(c0 + w) * 3 + 2];
  float* tok = tokens + (size_t)(c0 + w) * 256;
  for (int h = 0; h < 2; ++h) {
    {  // stage W3 col-half (32KB) -> [0,32K); H2 at [32K,64K) untouched
      const u32* s = (const u32*)w3L + h * 8192;
      u32* d = (u32*)lds;
#pragma unroll
      for (int q = 0; q < 32; ++q) d[q * 256 + t] = s[q * 256 + t];
    }
    __syncthreads();
    f32x4 acc3[2][8];
#pragma unroll
    for (int m = 0; m < 2; ++m)
#pragma unroll
      for (int n = 0; n < 8; ++n) acc3[m][n] = (f32x4){0.f, 0.f, 0.f, 0.f};
#pragma unroll
    for (int ks = 0; ks < 4; ++ks) {
      bf16x8 a[2];
#pragma unroll
      for (int m = 0; m < 2; ++m) {
        int row = w * 32 + m * 16 + l15;
        int byte = row * 256 + (ks * 32 + lg * 8) * 2;
        a[m] = *reinterpret_cast<const bf16x8*>(lds + 32768 + (byte ^ ((row & 7) << 4)));
      }
      const int kg = ks * 4 + lg;
#pragma unroll
      for (int n = 0; n < 8; ++n) {
        int idx = (((kg * 128) + (n * 16 + l15)) * 8) ^ ((kg & 7) * 8);
        bf16x8 bb = *reinterpret_cast<const bf16x8*>((const u16*)lds + idx);
        acc3[0][n] = MFMA16(a[0], bb, acc3[0][n]);
        acc3[1][n] = MFMA16(a[1], bb, acc3[1][n]);
      }
    }
#pragma unroll
    for (int n = 0; n < 8; ++n) {  // max over 32 neighbors + b3 + pos
      float vmx = acc3[0][n][0];
#pragma unroll
      for (int m = 0; m < 2; ++m)
#pragma unroll
        for (int r = 0; r < 4; ++r) vmx = fmaxf(vmx, acc3[m][n][r]);
      vmx = fmaxf(vmx, __shfl_xor(vmx, 16, 64));
      vmx = fmaxf(vmx, __shfl_xor(vmx, 32, 64));
      const int col = h * 128 + n * 16 + l15;
      if (lane < 16) {
        float pos = Wp[col * 3 + 0] * ccx + Wp[col * 3 + 1] * ccy +
                    Wp[col * 3 + 2] * ccz + bp[col] + b3[col];
        tok[col] = vmx + pos;
      }
    }
    __syncthreads();
  }
}

// ---------------------------------------------------------------------------
extern "C" void kernel_launch(void* const* d_in, const int* in_sizes, int n_in,
                              void* d_out, int out_size, void* d_ws, size_t ws_size,
                              hipStream_t stream) {
  const float* xyz = (const float*)d_in[0];
  const float* W1 = (const float*)d_in[1];
  const float* b1 = (const float*)d_in[2];
  const float* g1 = (const float*)d_in[3];
  const float* be1 = (const float*)d_in[4];
  const float* m1 = (const float*)d_in[5];
  const float* v1 = (const float*)d_in[6];
  const float* W2 = (const float*)d_in[7];
  const float* b2 = (const float*)d_in[8];
  const float* g2 = (const float*)d_in[9];
  const float* be2 = (const float*)d_in[10];
  const float* m2 = (const float*)d_in[11];
  const float* v2 = (const float*)d_in[12];
  const float* W3 = (const float*)d_in[13];
  const float* b3 = (const float*)d_in[14];
  const float* Wp = (const float*)d_in[15];
  const float* bp = (const float*)d_in[16];

  char* ws = (char*)d_ws;
  float* grouped = (float*)ws;                      // 4096*32*3 f32 = 1572864 B
  float* w1eff = (float*)(ws + 1572864);            // 64*4 f32     = 1024 B
  u16* w2L = (u16*)(ws + 1573888);                  // 8192 u16     = 16384 B
  float* t2 = (float*)(ws + 1590272);               // 128 f32      = 512 B
  u16* w3L = (u16*)(ws + 1590784);                  // 32768 u16    = 65536 B

  float* centers = (float*)d_out;                   // (8,512,3)
  float* tokens = (float*)d_out + 8 * 512 * 3;      // (8,512,256)

  prep_kernel<<<dim3(128), dim3(256), 0, stream>>>(W1, b1, g1, be1, m1, v1,
                                                   W2, b2, g2, be2, m2, v2, W3,
                                                   w1eff, w2L, t2, w3L);
  fps_kernel<<<dim3(8), dim3(1024), 0, stream>>>(xyz, centers);
  knn_kernel<<<dim3(512), dim3(512), 0, stream>>>(xyz, centers, grouped);
  mlp_kernel<<<dim3(1024), dim3(256), 0, stream>>>(grouped, w2L, w3L, w1eff, t2,
                                                   b3, Wp, bp, centers, tokens);
}

// Round 6
// 934.298 us; speedup vs baseline: 2.3545x; 1.0011x over previous
//
#include <hip/hip_runtime.h>

typedef unsigned int u32;
typedef unsigned long long u64;
typedef unsigned short u16;

#define DEVFN static __device__ __forceinline__

constexpr int NPTS = 16384;  // points per batch
constexpr int NC = 512;      // centers per batch
// B=8, K=32, FEAT=256

typedef __attribute__((ext_vector_type(8))) short bf16x8;
typedef __attribute__((ext_vector_type(4))) float f32x4;

#define MFMA16(a, b, c) __builtin_amdgcn_mfma_f32_16x16x32_bf16(a, b, c, 0, 0, 0)

DEVFN u16 bf16rne(float f) {
  u32 b = __float_as_uint(f);
  u32 r = (b + 0x7FFFu + ((b >> 16) & 1u)) >> 16;
  return (u16)r;
}

DEVFN u64 shflx64(u64 v, int m) {
  u32 lo = __shfl_xor((u32)v, m, 64);
  u32 hi = __shfl_xor((u32)(v >> 32), m, 64);
  return ((u64)hi << 32) | lo;
}
DEVFN u64 shfl64(u64 v, int src) {
  u32 lo = __shfl((u32)v, src, 64);
  u32 hi = __shfl((u32)(v >> 32), src, 64);
  return ((u64)hi << 32) | lo;
}

DEVFN void csw(u64& a, u64& b) {
  u64 lo = a < b ? a : b;
  u64 hi = a < b ? b : a;
  a = lo; b = hi;
}

DEVFN u32 spread3(u32 v) {  // 4 bits -> bits 0,3,6,9
  return (v & 1u) | ((v & 2u) << 2) | ((v & 4u) << 4) | ((v & 8u) << 6);
}

// ---------------------------------------------------------------------------
// FPS v5: identical structure to v4 (Morton clusters of 64 pts, 4 thr/cluster,
// all mutable state in registers, 1 barrier/iter) BUT with the register
// allocator pinned via amdgpu_waves_per_eu(4,4): the backend's occupancy
// heuristic targets the MAX of the waves/EU range (default 8 -> 64-reg
// budget -> spill). Pinning min=max=4 gives the 128-reg budget the 1024-thr
// workgroup already implies, so px/py/pz/mdkey (~110 regs) stay resident.
// ---------------------------------------------------------------------------
__global__ __attribute__((amdgpu_flat_work_group_size(1024, 1024)))
__attribute__((amdgpu_waves_per_eu(4, 4))) void fps_kernel(const float* __restrict__ xyz,
                                                           float* __restrict__ centers) {
  const int b = blockIdx.x;
  const int t = threadIdx.x;
  const int lane = t & 63;
  const int w = t >> 6;
  const float* xb = xyz + (size_t)b * NPTS * 3;

  __shared__ char smem[86016];               // padded: force 1 block/CU
  u32* hist = (u32*)smem;                    // [0, 8K)   2048 u32
  u16* soidx = (u16*)(smem + 8192);          // [8K, 40K) 16384 u16
  u64* skeybuf = (u64*)(smem + 40960);       // [40K, +256) 2x16 u64
  float* redB = (float*)(smem + 41216);      // 104 f32
  u32* redW = (u32*)(smem + 41664);          // 16 u32

  const u32 inf10 = __float_as_uint(1e10f);

  // ---- setup: global bbox + morton codes ----
  u32 mcode[16];
  {
    float ox[16], oy[16], oz[16];
    float lx = 1e30f, ly = 1e30f, lz = 1e30f;
    float hx = -1e30f, hy = -1e30f, hz = -1e30f;
#pragma unroll
    for (int j = 0; j < 16; ++j) {
      int p = t + j * 1024;
      ox[j] = xb[p * 3 + 0];
      oy[j] = xb[p * 3 + 1];
      oz[j] = xb[p * 3 + 2];
      lx = fminf(lx, ox[j]); hx = fmaxf(hx, ox[j]);
      ly = fminf(ly, oy[j]); hy = fmaxf(hy, oy[j]);
      lz = fminf(lz, oz[j]); hz = fmaxf(hz, oz[j]);
    }
#pragma unroll
    for (int s = 32; s; s >>= 1) {
      lx = fminf(lx, __shfl_xor(lx, s, 64)); hx = fmaxf(hx, __shfl_xor(hx, s, 64));
      ly = fminf(ly, __shfl_xor(ly, s, 64)); hy = fmaxf(hy, __shfl_xor(hy, s, 64));
      lz = fminf(lz, __shfl_xor(lz, s, 64)); hz = fmaxf(hz, __shfl_xor(hz, s, 64));
    }
    if (lane == 0) {
      redB[w * 6 + 0] = lx; redB[w * 6 + 1] = hx;
      redB[w * 6 + 2] = ly; redB[w * 6 + 3] = hy;
      redB[w * 6 + 4] = lz; redB[w * 6 + 5] = hz;
    }
    hist[t] = 0; hist[t + 1024] = 0;
    __syncthreads();
    if (t == 0) {
      float a0 = redB[0], a1 = redB[1], a2 = redB[2], a3 = redB[3], a4 = redB[4], a5 = redB[5];
      for (int q = 1; q < 16; ++q) {
        a0 = fminf(a0, redB[q * 6 + 0]); a1 = fmaxf(a1, redB[q * 6 + 1]);
        a2 = fminf(a2, redB[q * 6 + 2]); a3 = fmaxf(a3, redB[q * 6 + 3]);
        a4 = fminf(a4, redB[q * 6 + 4]); a5 = fmaxf(a5, redB[q * 6 + 5]);
      }
      redB[96] = a0; redB[97] = a1; redB[98] = a2;
      redB[99] = a3; redB[100] = a4; redB[101] = a5;
    }
    __syncthreads();
    const float glx = redB[96], ghx = redB[97];
    const float gly = redB[98], ghy = redB[99];
    const float glz = redB[100], ghz = redB[101];
    const float sx = 15.999f / fmaxf(ghx - glx, 1e-9f);
    const float sy = 15.999f / fmaxf(ghy - gly, 1e-9f);
    const float sz = 7.999f / fmaxf(ghz - glz, 1e-9f);
#pragma unroll
    for (int j = 0; j < 16; ++j) {
      int ix = min(15, max(0, (int)((ox[j] - glx) * sx)));
      int iy = min(15, max(0, (int)((oy[j] - gly) * sy)));
      int iz = min(7, max(0, (int)((oz[j] - glz) * sz)));
      mcode[j] = spread3((u32)ix) | (spread3((u32)iy) << 1) | (spread3((u32)iz) << 2);
    }
  }
  // ---- histogram (2048 bins) ----
#pragma unroll
  for (int j = 0; j < 16; ++j) atomicAdd(&hist[mcode[j]], 1u);
  __syncthreads();
  // ---- exclusive scan over 2048 bins ----
  {
    u32 h0 = hist[t * 2 + 0], h1 = hist[t * 2 + 1];
    u32 s = h0 + h1;
    u32 incl = s;
#pragma unroll
    for (int d = 1; d < 64; d <<= 1) {
      u32 n = __shfl_up(incl, d, 64);
      if (lane >= d) incl += n;
    }
    if (lane == 63) redW[w] = incl;
    __syncthreads();
    if (t == 0) {
      u32 run = 0;
      for (int q = 0; q < 16; ++q) { u32 tmp = redW[q]; redW[q] = run; run += tmp; }
    }
    __syncthreads();
    u32 exc = incl - s + redW[w];
    hist[t * 2 + 0] = exc;
    hist[t * 2 + 1] = exc + h0;
    __syncthreads();
  }
  // ---- scatter: sorted position -> original index ----
#pragma unroll
  for (int j = 0; j < 16; ++j) {
    u32 p = (u32)(t + j * 1024);
    u32 pos = atomicAdd(&hist[mcode[j]], 1u);
    soidx[pos] = (u16)p;
  }
  __syncthreads();
  // ---- gather: thread owns 16 consecutive sorted points of its cluster ----
  const u32 spbase = (u32)((t >> 2) * 64 + (t & 3) * 16);
  float px[16], py[16], pz[16];
  u64 mdkey[16];
#pragma unroll
  for (int j = 0; j < 16; ++j) {
    u32 oidx = (u32)soidx[spbase + j];
    px[j] = xb[oidx * 3 + 0];
    py[j] = xb[oidx * 3 + 1];
    pz[j] = xb[oidx * 3 + 2];
    mdkey[j] = ((u64)inf10 << 32) | (u64)(16383u - oidx);
  }
  // ---- cluster bbox in registers (2-step shuffle over the 4-lane group) ----
  float bxl = px[0], bxh = px[0], byl = py[0], byh = py[0], bzl = pz[0], bzh = pz[0];
#pragma unroll
  for (int j = 1; j < 16; ++j) {
    bxl = fminf(bxl, px[j]); bxh = fmaxf(bxh, px[j]);
    byl = fminf(byl, py[j]); byh = fmaxf(byh, py[j]);
    bzl = fminf(bzl, pz[j]); bzh = fmaxf(bzh, pz[j]);
  }
#pragma unroll
  for (int s = 1; s <= 2; s <<= 1) {
    bxl = fminf(bxl, __shfl_xor(bxl, s, 64)); bxh = fmaxf(bxh, __shfl_xor(bxh, s, 64));
    byl = fminf(byl, __shfl_xor(byl, s, 64)); byh = fmaxf(byh, __shfl_xor(byh, s, 64));
    bzl = fminf(bzl, __shfl_xor(bzl, s, 64)); bzh = fmaxf(bzh, __shfl_xor(bzh, s, 64));
  }
  float cx = xb[0], cy = xb[1], cz = xb[2];
  if (t == 0) {
    centers[(b * NC) * 3 + 0] = cx;
    centers[(b * NC) * 3 + 1] = cy;
    centers[(b * NC) * 3 + 2] = cz;
  }
  u64 mdmkey = (u64)inf10 << 32;  // cluster-max key (group-uniform)

  // ---- main loop: 1 barrier per iteration ----
  for (int i = 1; i < NC; ++i) {
    float ax = fmaxf(0.f, fmaxf(__fsub_rn(bxl, cx), __fsub_rn(cx, bxh)));
    float ay = fmaxf(0.f, fmaxf(__fsub_rn(byl, cy), __fsub_rn(cy, byh)));
    float az = fmaxf(0.f, fmaxf(__fsub_rn(bzl, cz), __fsub_rn(cz, bzh)));
    float dlb = __fadd_rn(__fadd_rn(__fmul_rn(ax, ax), __fmul_rn(ay, ay)), __fmul_rn(az, az));
    if (dlb < __uint_as_float((u32)(mdmkey >> 32))) {  // group-uniform branch
      u64 lmax = 0ull;
#pragma unroll
      for (int j = 0; j < 16; ++j) {
        float dx = __fsub_rn(px[j], cx);
        float dy = __fsub_rn(py[j], cy);
        float dz = __fsub_rn(pz[j], cz);
        float d = __fadd_rn(__fadd_rn(__fmul_rn(dx, dx), __fmul_rn(dy, dy)), __fmul_rn(dz, dz));
        u64 nk = ((u64)__float_as_uint(d) << 32) | (mdkey[j] & 0xFFFFFFFFull);
        u64 k = nk < mdkey[j] ? nk : mdkey[j];  // md = min(md, d)
        mdkey[j] = k;
        lmax = k > lmax ? k : lmax;
      }
      u64 o1 = shflx64(lmax, 1); lmax = o1 > lmax ? o1 : lmax;
      u64 o2 = shflx64(lmax, 2); lmax = o2 > lmax ? o2 : lmax;
      mdmkey = lmax;
    }
    u64 wk = mdmkey;  // wave max over 16 clusters (groups uniform -> start at 4)
#pragma unroll
    for (int s = 4; s <= 32; s <<= 1) { u64 o = shflx64(wk, s); wk = o > wk ? o : wk; }
    if (lane == 0) skeybuf[(i & 1) * 16 + w] = wk;
    __syncthreads();
    u64 gk = skeybuf[(i & 1) * 16 + (lane & 15)];
#pragma unroll
    for (int s = 1; s <= 8; s <<= 1) { u64 o = shflx64(gk, s); gk = o > gk ? o : gk; }
    u32 ow = 16383u - (u32)gk;  // winner original index
    ow = __builtin_amdgcn_readfirstlane(ow);
    cx = xb[ow * 3 + 0]; cy = xb[ow * 3 + 1]; cz = xb[ow * 3 + 2];
    if (t == 0) {
      centers[(b * NC + i) * 3 + 0] = cx;
      centers[(b * NC + i) * 3 + 1] = cy;
      centers[(b * NC + i) * 3 + 2] = cz;
    }
  }
}

// ---------------------------------------------------------------------------
// KNN: 8 waves/block, wave = one center. Exact top-32 set by (d, idx).
// ---------------------------------------------------------------------------
__global__ __launch_bounds__(512) void knn_kernel(const float* __restrict__ xyz,
                                                  const float* __restrict__ centers,
                                                  float* __restrict__ grouped) {
  __shared__ float spts[1024 * 3];
  __shared__ u64 cand[8][192];
  __shared__ int ccnt[8];
  const int t = threadIdx.x;
  const int lane = t & 63;
  const int w = t >> 6;
  const int cg = blockIdx.x * 8 + w;   // global center id
  const int b = cg >> 9;               // / 512
  const float* xb = xyz + (size_t)b * NPTS * 3;
  const float cx = centers[cg * 3 + 0];
  const float cy = centers[cg * 3 + 1];
  const float cz = centers[cg * 3 + 2];
  if (lane == 0) ccnt[w] = 0;

  // phase 1: per-lane min (packed (d,idx))
  u64 lmin = ~0ull;
  for (int ch = 0; ch < 16; ++ch) {
    __syncthreads();
    const float* src = xb + ch * 1024 * 3;
#pragma unroll
    for (int q = 0; q < 6; ++q) spts[q * 512 + t] = src[q * 512 + t];
    __syncthreads();
#pragma unroll
    for (int j = 0; j < 16; ++j) {
      int p = lane + j * 64;
      float dx = __fsub_rn(cx, spts[p * 3 + 0]);
      float dy = __fsub_rn(cy, spts[p * 3 + 1]);
      float dz = __fsub_rn(cz, spts[p * 3 + 2]);
      float d = __fadd_rn(__fadd_rn(__fmul_rn(dx, dx), __fmul_rn(dy, dy)), __fmul_rn(dz, dz));
      u64 kk = ((u64)__float_as_uint(d) << 32) | (u64)(u32)(ch * 1024 + p);
      lmin = kk < lmin ? kk : lmin;
    }
  }
  // bitonic sort (ascending) of 64 lane-minima; tau = 32nd smallest
  u64 v = lmin;
  for (int k = 2; k <= 64; k <<= 1)
    for (int j = k >> 1; j > 0; j >>= 1) {
      u64 o = shflx64(v, j);
      bool up = ((lane & k) == 0);
      bool lowr = ((lane & j) == 0);
      u64 mn = v < o ? v : o;
      u64 mx = v < o ? o : v;
      v = (lowr == up) ? mn : mx;
    }
  u64 tau = shfl64(v, 31);
  float tf = __uint_as_float((u32)(tau >> 32));

  // phase 2: collect candidates d <= tf  (guaranteed >= 32 of them)
  for (int ch = 0; ch < 16; ++ch) {
    __syncthreads();
    const float* src = xb + ch * 1024 * 3;
#pragma unroll
    for (int q = 0; q < 6; ++q) spts[q * 512 + t] = src[q * 512 + t];
    __syncthreads();
#pragma unroll
    for (int j = 0; j < 16; ++j) {
      int p = lane + j * 64;
      float dx = __fsub_rn(cx, spts[p * 3 + 0]);
      float dy = __fsub_rn(cy, spts[p * 3 + 1]);
      float dz = __fsub_rn(cz, spts[p * 3 + 2]);
      float d = __fadd_rn(__fadd_rn(__fmul_rn(dx, dx), __fmul_rn(dy, dy)), __fmul_rn(dz, dz));
      if (d <= tf) {
        int pos = atomicAdd(&ccnt[w], 1);
        if (pos < 192) cand[w][pos] = ((u64)__float_as_uint(d) << 32) | (u64)(u32)(ch * 1024 + p);
      }
    }
  }
  __syncthreads();
  int cnt = ccnt[w];
  u32 myn = 0u;  // lane r (<32) keeps r-th nearest neighbor's index
  if (cnt <= 192) {
    u64 c0 = (lane < cnt) ? cand[w][lane] : ~0ull;
    u64 c1 = (64 + lane < cnt) ? cand[w][64 + lane] : ~0ull;
    u64 c2 = (128 + lane < cnt) ? cand[w][128 + lane] : ~0ull;
    csw(c0, c1); csw(c1, c2); csw(c0, c1);  // c0<=c1<=c2
    for (int r = 0; r < 32; ++r) {
      u64 wm = c0;
      for (int s = 32; s; s >>= 1) {
        u64 o = shflx64(wm, s);
        wm = o < wm ? o : wm;
      }
      if (c0 == wm) { c0 = c1; c1 = c2; c2 = ~0ull; }
      if (lane == r) myn = (u32)wm;
    }
  } else {
    // exact slow fallback (astronomically rare): ascending extraction
    u64 last = 0ull;
    for (int r = 0; r < 32; ++r) {
      u64 bb = ~0ull;
      for (int j = 0; j < 256; ++j) {
        int p = lane + j * 64;
        float dx = __fsub_rn(cx, xb[p * 3 + 0]);
        float dy = __fsub_rn(cy, xb[p * 3 + 1]);
        float dz = __fsub_rn(cz, xb[p * 3 + 2]);
        float d = __fadd_rn(__fadd_rn(__fmul_rn(dx, dx), __fmul_rn(dy, dy)), __fmul_rn(dz, dz));
        u64 kk = ((u64)__float_as_uint(d) << 32) | (u64)(u32)p;
        if (r == 0 || kk > last)
          if (kk < bb) bb = kk;
      }
      for (int s = 32; s; s >>= 1) {
        u64 o = shflx64(bb, s);
        bb = o < bb ? o : bb;
      }
      last = bb;
      if (lane == r) myn = (u32)bb;
    }
  }
  if (lane < 32) {
    const float nx = xb[(size_t)myn * 3 + 0];
    const float ny = xb[(size_t)myn * 3 + 1];
    const float nz = xb[(size_t)myn * 3 + 2];
    float* gp = grouped + ((size_t)cg * 32 + lane) * 3;
    gp[0] = __fsub_rn(nx, cx);
    gp[1] = __fsub_rn(ny, cy);
    gp[2] = __fsub_rn(nz, cz);
  }
}

// ---------------------------------------------------------------------------
// Weight prep: fold eval-BN into weights, bf16 + MFMA-fragment-swizzled
// layouts for W2/W3 so the MLP kernel stages LDS with a linear copy.
// ---------------------------------------------------------------------------
__global__ __launch_bounds__(256) void prep_kernel(
    const float* __restrict__ W1, const float* __restrict__ b1,
    const float* __restrict__ g1, const float* __restrict__ be1,
    const float* __restrict__ m1, const float* __restrict__ v1,
    const float* __restrict__ W2, const float* __restrict__ b2,
    const float* __restrict__ g2, const float* __restrict__ be2,
    const float* __restrict__ m2, const float* __restrict__ v2,
    const float* __restrict__ W3,
    float* __restrict__ w1eff, u16* __restrict__ w2L,
    float* __restrict__ t2, u16* __restrict__ w3L) {
  const int tid = blockIdx.x * 256 + threadIdx.x;  // 128 blocks -> 32768
  if (tid < 64) {
    float s = g1[tid] / sqrtf(v1[tid] + 1e-5f);
    w1eff[tid * 4 + 0] = W1[tid * 3 + 0] * s;
    w1eff[tid * 4 + 1] = W1[tid * 3 + 1] * s;
    w1eff[tid * 4 + 2] = W1[tid * 3 + 2] * s;
    w1eff[tid * 4 + 3] = (b1[tid] - m1[tid]) * s + be1[tid];
  }
  if (tid < 128) {
    float s = g2[tid] / sqrtf(v2[tid] + 1e-5f);
    t2[tid] = (b2[tid] - m2[tid]) * s + be2[tid];
  }
  if (tid < 8192) {  // W2eff (128 out x 64 in), bn-scaled, as B-fragments
    int i = tid & 63, o = tid >> 6;
    float s = g2[o] / sqrtf(v2[o] + 1e-5f);
    int kg = i >> 3, j = i & 7;
    w2L[((((kg * 128) + o) * 8) ^ ((kg & 7) * 8)) + j] = bf16rne(W2[o * 64 + i] * s);
  }
  if (tid < 32768) {  // W3 (256 out x 128 in) as B-fragments, split in col-halves
    int i = tid & 127, o = tid >> 7;
    int kg = i >> 3, j = i & 7;
    int h = o >> 7, colh = o & 127;
    w3L[h * 16384 + ((((kg * 128) + colh) * 8) ^ ((kg & 7) * 8)) + j] = bf16rne(W3[o * 128 + i]);
  }
}

// ---------------------------------------------------------------------------
// MLP: 4 centers (128 rows) per 256-thread block; wave = one center.
// L1 on VALU (K=3), L2/L3 as bf16 MFMA GEMMs; fused max-pool + pos epilogue.
// LDS (64KB): [0,16K)=W2 (later W3 half over [0,32K)); [16K,32K)=H1; [32K,64K)=H2.
// ---------------------------------------------------------------------------
__global__ __launch_bounds__(256) void mlp_kernel(
    const float* __restrict__ grouped, const u16* __restrict__ w2L,
    const u16* __restrict__ w3L, const float* __restrict__ w1eff,
    const float* __restrict__ t2, const float* __restrict__ b3,
    const float* __restrict__ Wp, const float* __restrict__ bp,
    const float* __restrict__ centers, float* __restrict__ tokens) {
  __shared__ char lds[65536];
  const int t = threadIdx.x;
  const int lane = t & 63;
  const int w = t >> 6;
  const int l15 = lane & 15;
  const int lg = lane >> 4;
  const int c0 = blockIdx.x * 4;
  {  // stage W2 -> [0,16K)
    const u32* s = (const u32*)w2L;
    u32* d = (u32*)lds;
#pragma unroll
    for (int q = 0; q < 16; ++q) d[q * 256 + t] = s[q * 256 + t];
  }
  {  // H1 = relu(X @ W1eff^T + b1eff), bf16, swizzled -> [16K,32K)
    const int row = t & 127;
    const int oh = (t >> 7) * 32;
    const int cg = c0 + (row >> 5);
    const float* gp = grouped + ((size_t)cg * 32 + (row & 31)) * 3;
    const float gx = gp[0], gy = gp[1], gz = gp[2];
    u16 hv[32];
#pragma unroll
    for (int o = 0; o < 32; ++o) {
      const float4 wvv = ((const float4*)w1eff)[oh + o];
      float h = fmaxf(0.f, gx * wvv.x + gy * wvv.y + gz * wvv.z + wvv.w);
      hv[o] = bf16rne(h);
    }
#pragma unroll
    for (int c4 = 0; c4 < 4; ++c4) {
      uint4 pk;
      pk.x = (u32)hv[c4 * 8 + 0] | ((u32)hv[c4 * 8 + 1] << 16);
      pk.y = (u32)hv[c4 * 8 + 2] | ((u32)hv[c4 * 8 + 3] << 16);
      pk.z = (u32)hv[c4 * 8 + 4] | ((u32)hv[c4 * 8 + 5] << 16);
      pk.w = (u32)hv[c4 * 8 + 6] | ((u32)hv[c4 * 8 + 7] << 16);
      int byte = row * 128 + oh * 2 + c4 * 16;
      *reinterpret_cast<uint4*>(lds + 16384 + (byte ^ ((row & 7) << 4))) = pk;
    }
  }
  __syncthreads();
  // GEMM2: H2(32x128) = H1(32x64) @ W2eff^T, per wave
  f32x4 acc2[2][8];
#pragma unroll
  for (int m = 0; m < 2; ++m)
#pragma unroll
    for (int n = 0; n < 8; ++n) acc2[m][n] = (f32x4){0.f, 0.f, 0.f, 0.f};
#pragma unroll
  for (int ks = 0; ks < 2; ++ks) {
    bf16x8 a[2];
#pragma unroll
    for (int m = 0; m < 2; ++m) {
      int row = w * 32 + m * 16 + l15;
      int byte = row * 128 + (ks * 32 + lg * 8) * 2;
      a[m] = *reinterpret_cast<const bf16x8*>(lds + 16384 + (byte ^ ((row & 7) << 4)));
    }
    const int kg = ks * 4 + lg;
#pragma unroll
    for (int n = 0; n < 8; ++n) {
      int idx = (((kg * 128) + (n * 16 + l15)) * 8) ^ ((kg & 7) * 8);
      bf16x8 bb = *reinterpret_cast<const bf16x8*>((const u16*)lds + idx);
      acc2[0][n] = MFMA16(a[0], bb, acc2[0][n]);
      acc2[1][n] = MFMA16(a[1], bb, acc2[1][n]);
    }
  }
#pragma unroll
  for (int n = 0; n < 8; ++n) {  // relu(acc + t2) -> H2 bf16 swizzled
    const int col = n * 16 + l15;
    const float t2v = t2[col];
#pragma unroll
    for (int m = 0; m < 2; ++m)
#pragma unroll
      for (int r = 0; r < 4; ++r) {
        float vv = fmaxf(0.f, acc2[m][n][r] + t2v);
        int row = w * 32 + m * 16 + lg * 4 + r;
        int byte = row * 256 + col * 2;
        *reinterpret_cast<u16*>(lds + 32768 + (byte ^ ((row & 7) << 4))) = bf16rne(vv);
      }
  }
  __syncthreads();
  const float ccx = centers[(c0 + w) * 3 + 0];
  const float ccy = centers[(c0 + w) * 3 + 1];
  const float ccz = centers[(c0 + w) * 3 + 2];
  float* tok = tokens + (size_t)(c0 + w) * 256;
  for (int h = 0; h < 2; ++h) {
    {  // stage W3 col-half (32KB) -> [0,32K); H2 at [32K,64K) untouched
      const u32* s = (const u32*)w3L + h * 8192;
      u32* d = (u32*)lds;
#pragma unroll
      for (int q = 0; q < 32; ++q) d[q * 256 + t] = s[q * 256 + t];
    }
    __syncthreads();
    f32x4 acc3[2][8];
#pragma unroll
    for (int m = 0; m < 2; ++m)
#pragma unroll
      for (int n = 0; n < 8; ++n) acc3[m][n] = (f32x4){0.f, 0.f, 0.f, 0.f};
#pragma unroll
    for (int ks = 0; ks < 4; ++ks) {
      bf16x8 a[2];
#pragma unroll
      for (int m = 0; m < 2; ++m) {
        int row = w * 32 + m * 16 + l15;
        int byte = row * 256 + (ks * 32 + lg * 8) * 2;
        a[m] = *reinterpret_cast<const bf16x8*>(lds + 32768 + (byte ^ ((row & 7) << 4)));
      }
      const int kg = ks * 4 + lg;
#pragma unroll
      for (int n = 0; n < 8; ++n) {
        int idx = (((kg * 128) + (n * 16 + l15)) * 8) ^ ((kg & 7) * 8);
        bf16x8 bb = *reinterpret_cast<const bf16x8*>((const u16*)lds + idx);
        acc3[0][n] = MFMA16(a[0], bb, acc3[0][n]);
        acc3[1][n] = MFMA16(a[1], bb, acc3[1][n]);
      }
    }
#pragma unroll
    for (int n = 0; n < 8; ++n) {  // max over 32 neighbors + b3 + pos
      float vmx = acc3[0][n][0];
#pragma unroll
      for (int m = 0; m < 2; ++m)
#pragma unroll
        for (int r = 0; r < 4; ++r) vmx = fmaxf(vmx, acc3[m][n][r]);
      vmx = fmaxf(vmx, __shfl_xor(vmx, 16, 64));
      vmx = fmaxf(vmx, __shfl_xor(vmx, 32, 64));
      const int col = h * 128 + n * 16 + l15;
      if (lane < 16) {
        float pos = Wp[col * 3 + 0] * ccx + Wp[col * 3 + 1] * ccy +
                    Wp[col * 3 + 2] * ccz + bp[col] + b3[col];
        tok[col] = vmx + pos;
      }
    }
    __syncthreads();
  }
}

// ---------------------------------------------------------------------------
extern "C" void kernel_launch(void* const* d_in, const int* in_sizes, int n_in,
                              void* d_out, int out_size, void* d_ws, size_t ws_size,
                              hipStream_t stream) {
  const float* xyz = (const float*)d_in[0];
  const float* W1 = (const float*)d_in[1];
  const float* b1 = (const float*)d_in[2];
  const float* g1 = (const float*)d_in[3];
  const float* be1 = (const float*)d_in[4];
  const float* m1 = (const float*)d_in[5];
  const float* v1 = (const float*)d_in[6];
  const float* W2 = (const float*)d_in[7];
  const float* b2 = (const float*)d_in[8];
  const float* g2 = (const float*)d_in[9];
  const float* be2 = (const float*)d_in[10];
  const float* m2 = (const float*)d_in[11];
  const float* v2 = (const float*)d_in[12];
  const float* W3 = (const float*)d_in[13];
  const float* b3 = (const float*)d_in[14];
  const float* Wp = (const float*)d_in[15];
  const float* bp = (const float*)d_in[16];

  char* ws = (char*)d_ws;
  float* grouped = (float*)ws;                      // 4096*32*3 f32 = 1572864 B
  float* w1eff = (float*)(ws + 1572864);            // 64*4 f32     = 1024 B
  u16* w2L = (u16*)(ws + 1573888);                  // 8192 u16     = 16384 B
  float* t2 = (float*)(ws + 1590272);               // 128 f32      = 512 B
  u16* w3L = (u16*)(ws + 1590784);                  // 32768 u16    = 65536 B

  float* centers = (float*)d_out;                   // (8,512,3)
  float* tokens = (float*)d_out + 8 * 512 * 3;      // (8,512,256)

  prep_kernel<<<dim3(128), dim3(256), 0, stream>>>(W1, b1, g1, be1, m1, v1,
                                                   W2, b2, g2, be2, m2, v2, W3,
                                                   w1eff, w2L, t2, w3L);
  fps_kernel<<<dim3(8), dim3(1024), 0, stream>>>(xyz, centers);
  knn_kernel<<<dim3(512), dim3(512), 0, stream>>>(xyz, centers, grouped);
  mlp_kernel<<<dim3(1024), dim3(256), 0, stream>>>(grouped, w2L, w3L, w1eff, t2,
                                                   b3, Wp, bp, centers, tokens);
}